// Round 1
// baseline (5050.557 us; speedup 1.0000x reference)
//
#include <hip/hip_runtime.h>
#include <math.h>

typedef unsigned int u32;
typedef unsigned long long u64;

#define B_ 16
#define L_ 1024
#define H_ 8
#define E_ 64
#define C_ 512            // H_*E_
#define NB_SEL 8          // blocks per batch in radix-select passes
#define PK_CAP 262144     // per-b peak value capacity (C_*511 max = 261632)

__device__ __forceinline__ u32 f2key(float f) {
  u32 u = __float_as_uint(f);
  return (u & 0x80000000u) ? ~u : (u | 0x80000000u);
}
__device__ __forceinline__ float key2f(u32 k) {
  u32 u = (k & 0x80000000u) ? (k ^ 0x80000000u) : ~k;
  return __uint_as_float(u);
}

// ---------------------------------------------------------------------------
// K_init: zero the small control state (ws is re-poisoned 0xAA every launch)
// ---------------------------------------------------------------------------
__global__ void k_init(u32* histA, u32* histB, u32* done, u32* peak_cnt,
                       double* s1, double* s2) {
  int tid = threadIdx.x;
  for (int i = tid; i < 16 * 256; i += 256) { histA[i] = 0; histB[i] = 0; }
  if (tid < 48) done[tid] = 0;
  if (tid < 16) { peak_cnt[tid] = 0; s1[tid] = 0.0; s2[tid] = 0.0; }
}

// ---------------------------------------------------------------------------
// K1: circular cross-correlation, fp32 direct.
// corr[b, c=h*64+e, tau] = sum_t q[t]*k[(t-tau) mod Ls], q/k pooled on the fly.
// Block: 256 thr = 64 e-lanes x 4 slots; each thread: 32 consecutive tau.
// Register-rotated k window: per t-step 2 ds_read_b32 + 32 v_fma_f32.
// ---------------------------------------------------------------------------
__launch_bounds__(256, 2)
__global__ void k_corr(const float* __restrict__ Q, const float* __restrict__ K,
                       float* __restrict__ corr, int Ls, int s) {
  __shared__ float qs[64 * 64];     // [t_local][e]
  __shared__ float ks[192 * 64];    // [j][e]; reused as transpose buffer
  const int tid = threadIdx.x;
  const int e = tid & 63, slot = tid >> 6;
  const int slot32 = slot << 5;
  const int tau0 = blockIdx.x << 7;         // *128
  const int bh = blockIdx.y;
  const int b = bh >> 3, h = bh & 7;
  const int Lmask = Ls - 1;
  const size_t base_q = (size_t)b * L_ * C_ + (size_t)h * 64 + e;

  float acc[32];
#pragma unroll
  for (int i = 0; i < 32; ++i) acc[i] = 0.f;
  float w[32];

  const int nchunk = Ls >> 6;
  for (int chunk = 0; chunk < nchunk; ++chunk) {
    const int t0 = chunk << 6;
    if (chunk) __syncthreads();
    // stage q rows (pooled) ------------------------------------------------
    for (int j = slot; j < 64; j += 4) {
      int traw = (t0 + j) * s;
      float v;
      if (s == 1) v = Q[base_q + (size_t)traw * C_];
      else if (s == 2)
        v = (Q[base_q + (size_t)traw * C_] + Q[base_q + (size_t)(traw + 1) * C_]) * 0.5f;
      else
        v = ((Q[base_q + (size_t)traw * C_] + Q[base_q + (size_t)(traw + 1) * C_]) +
             (Q[base_q + (size_t)(traw + 2) * C_] + Q[base_q + (size_t)(traw + 3) * C_])) * 0.25f;
      qs[j * 64 + e] = v;
    }
    // stage k rows (pooled, wrapped) --------------------------------------
    for (int j = slot; j < 192; j += 4) {
      int tk = (t0 - tau0 - 127 + j + 2048) & Lmask;  // 2048 is mult of Ls (256/512/1024)
      int traw = tk * s;
      float v;
      if (s == 1) v = K[base_q + (size_t)traw * C_];
      else if (s == 2)
        v = (K[base_q + (size_t)traw * C_] + K[base_q + (size_t)(traw + 1) * C_]) * 0.5f;
      else
        v = ((K[base_q + (size_t)traw * C_] + K[base_q + (size_t)(traw + 1) * C_]) +
             (K[base_q + (size_t)(traw + 2) * C_] + K[base_q + (size_t)(traw + 3) * C_])) * 0.25f;
      ks[j * 64 + e] = v;
    }
    __syncthreads();
    if (chunk == 0) {
#pragma unroll
      for (int i = 0; i < 32; ++i) w[i] = ks[(127 - slot32 - i) * 64 + e];
    }
#pragma unroll
    for (int j = 0; j < 64; ++j) {
      float qv = qs[j * 64 + e];
#pragma unroll
      for (int i = 0; i < 32; ++i) acc[i] = fmaf(qv, w[i], acc[i]);
#pragma unroll
      for (int i = 31; i > 0; --i) w[i] = w[i - 1];
      w[0] = ks[(j + 128 - slot32) * 64 + e];
    }
  }
  // transpose in LDS, coalesced write (tau-contiguous rows) ----------------
  __syncthreads();
  float* wt = ks;  // 128*65 = 8320 floats <= 12288
#pragma unroll
  for (int i = 0; i < 32; ++i) wt[(slot32 + i) * 65 + e] = acc[i];
  __syncthreads();
  const int to = tid & 127;
  const size_t cbase = ((size_t)b * C_ + (size_t)h * 64) * Ls + tau0 + to;
  for (int cr = tid >> 7; cr < 64; cr += 2)
    corr[cbase + (size_t)cr * Ls] = wt[to * 65 + cr];
}

// ---------------------------------------------------------------------------
// K2: per-b stats (sum, sumsq), cm (channel-mean per tau), peak detection,
// peak-value compaction + level-0 (top 8 bit) histogram.
// Grid: (Ls/256, B). One thread owns one tau; loop over channels.
// ---------------------------------------------------------------------------
__global__ void k_stats(const float* __restrict__ corr, float* __restrict__ cm,
                        double* s1, double* s2, u32* peak_cnt, u32* histA,
                        u32* pk_buf, int Ls) {
  __shared__ float row[258];
  __shared__ u32 hist_s[256];
  __shared__ double w1s[4], w2s[4];
  const int tid = threadIdx.x;
  const int b = blockIdx.y;
  const int tau0 = blockIdx.x << 8;
  const int tg = tau0 + tid;
  const int lane = tid & 63;
  hist_s[tid] = 0;
  float cm_acc = 0.f;
  double ls1 = 0.0, ls2 = 0.0;
  const size_t rb = (size_t)b * C_ * Ls;
  for (int c = 0; c < C_; ++c) {
    __syncthreads();
    const float* src = corr + rb + (size_t)c * Ls + tau0;
    row[tid + 1] = src[tid];
    if (tid == 0) row[0] = (tau0 > 0) ? src[-1] : 0.f;
    if (tid == 1) row[257] = (tau0 + 256 < Ls) ? src[256] : 0.f;
    __syncthreads();
    float v = row[tid + 1];
    cm_acc += v;
    ls1 += (double)v;
    ls2 += (double)v * (double)v;
    bool pk = (tg >= 1) && (tg <= Ls - 2) && (v > row[tid]) && (v > row[tid + 2]);
    u64 mask = __ballot(pk);
    if (mask) {
      int cnt = __popcll(mask);
      u32 base = 0;
      if (lane == 0) base = atomicAdd(&peak_cnt[b], (u32)cnt);
      base = __shfl(base, 0, 64);
      if (pk) {
        u32 key = f2key(v);
        atomicAdd(&hist_s[key >> 24], 1u);
        u32 pos = base + (u32)__popcll(mask & ((1ull << lane) - 1ull));
        pk_buf[(size_t)b * PK_CAP + pos] = key;
      }
    }
  }
  cm[b * 1024 + tg] = cm_acc * (1.0f / C_);
  // block-reduce double sums -> global atomics
  for (int off = 32; off; off >>= 1) {
    ls1 += __shfl_down(ls1, off, 64);
    ls2 += __shfl_down(ls2, off, 64);
  }
  if (lane == 0) { w1s[tid >> 6] = ls1; w2s[tid >> 6] = ls2; }
  __syncthreads();
  if (tid == 0) {
    atomicAdd(&s1[b], w1s[0] + w1s[1] + w1s[2] + w1s[3]);
    atomicAdd(&s2[b], w2s[0] + w2s[1] + w2s[2] + w2s[3]);
  }
  if (hist_s[tid]) atomicAdd(&histA[b * 256 + tid], hist_s[tid]);
}

// ---------------------------------------------------------------------------
// K3: pk count from cm, MLP -> kvals, level-0 radix scan, state init, and
// cleanup of s1/s2/histA for reuse. Single block.
// ---------------------------------------------------------------------------
__global__ void k_mlp(const float* __restrict__ cm, double* s1, double* s2,
                      const u32* peak_cnt, u32* histA, int* kvals, int* rank_s,
                      u32* prefix_s, u32* active, float* thresh,
                      const float* w1, const float* b1, const float* w2,
                      const float* b2, const float* w3, const float* b3, int Ls) {
  const int tid = threadIdx.x;
  __shared__ int red_i[4];
  __shared__ float energy_s;
  if (tid == 0) {
    double tot = 0.0;
    for (int b = 0; b < 16; ++b) tot += s2[b];
    energy_s = (float)(tot / (16.0 * (double)Ls));
  }
  __syncthreads();
  for (int b = 0; b < 16; ++b) {
    int cnt = 0;
    for (int t = 1 + tid; t <= Ls - 2; t += 256) {
      float v = cm[b * 1024 + t];
      cnt += (v > cm[b * 1024 + t - 1]) && (v > cm[b * 1024 + t + 1]);
    }
    for (int off = 32; off; off >>= 1) cnt += __shfl_down(cnt, off, 64);
    if ((tid & 63) == 0) red_i[tid >> 6] = cnt;
    __syncthreads();
    if (tid == 0) {
      int pk = red_i[0] + red_i[1] + red_i[2] + red_i[3];
      double N = (double)C_ * (double)Ls;
      double var_d = (s2[b] - s1[b] * s1[b] / N) / (N - 1.0);
      float f0 = energy_s, f1 = (float)var_d, f2 = (float)pk;
      float h1[32];
      for (int j = 0; j < 32; ++j)
        h1[j] = fmaxf(0.f, w1[j * 3] * f0 + w1[j * 3 + 1] * f1 + w1[j * 3 + 2] * f2 + b1[j]);
      float h2[16];
      for (int j = 0; j < 16; ++j) {
        float a = b2[j];
        for (int i = 0; i < 32; ++i) a += w2[j * 32 + i] * h1[i];
        h2[j] = fmaxf(0.f, a);
      }
      float z = b3[0];
      for (int i = 0; i < 16; ++i) z += w3[i] * h2[i];
      float ratio = 1.0f / (1.0f + __expf(-z));
      int kv = (int)(ratio * (float)Ls);
      kv = min(max(kv, 1), Ls);
      kvals[b] = kv;
      int cntb = (int)peak_cnt[b];
      int act = cntb > kv;
      active[b] = (u32)act;
      thresh[b] = -INFINITY;
      if (act) {
        int r = kv, acc0 = 0;
        u32 pref = 0;
        for (int bin = 255; bin >= 0; --bin) {
          int n = acc0 + (int)histA[b * 256 + bin];
          if (n >= r) { pref = (u32)bin << 24; r -= acc0; break; }
          acc0 = n;
        }
        prefix_s[b] = pref;
        rank_s[b] = r;
      }
    }
    __syncthreads();
    histA[b * 256 + tid] = 0;                       // ready for level 2
    if (tid == 0) { s1[b] = 0.0; s2[b] = 0.0; }     // ready for next scale
    __syncthreads();
  }
}

// ---------------------------------------------------------------------------
// K_sel (levels 1..3): 8-bit radix refinement, ticket-pattern finisher.
// Grid: 16*NB_SEL blocks; block handles a slice of batch b's peak keys.
// ---------------------------------------------------------------------------
__global__ void k_select(const u32* __restrict__ pk_buf, u32* peak_cnt,
                         const u32* active, int* rank_s, u32* prefix_s,
                         u32* hist, u32* done, float* thresh, int level) {
  const int tid = threadIdx.x;
  const int b = blockIdx.x / NB_SEL;
  const int blk = blockIdx.x % NB_SEL;
  __shared__ u32 hist_s[256];
  hist_s[tid] = 0;
  __syncthreads();
  const int act = (int)active[b];
  const u32 cnt = peak_cnt[b];
  if (act) {
    const u32 pref = prefix_s[b];
    const int hi_sh = 32 - 8 * level;
    const int b_sh = 24 - 8 * level;
    const u32 lo = (u32)(((u64)cnt * (u64)blk) / NB_SEL);
    const u32 hi = (u32)(((u64)cnt * (u64)(blk + 1)) / NB_SEL);
    const u32* src = pk_buf + (size_t)b * PK_CAP;
    for (u32 i = lo + tid; i < hi; i += 256) {
      u32 key = src[i];
      if ((key >> hi_sh) == (pref >> hi_sh))
        atomicAdd(&hist_s[(key >> b_sh) & 255u], 1u);
    }
  }
  __syncthreads();
  if (hist_s[tid]) atomicAdd(&hist[b * 256 + tid], hist_s[tid]);
  __threadfence();
  __syncthreads();
  if (tid == 0) {
    u32 t = atomicAdd(&done[(level - 1) * 16 + b], 1u);
    if (t == NB_SEL - 1) {
      done[(level - 1) * 16 + b] = 0;
      __threadfence();
      if (act) {
        int r = rank_s[b], acc0 = 0, bsel = 0;
        for (int bin = 255; bin >= 0; --bin) {
          int n = acc0 + (int)atomicAdd(&hist[b * 256 + bin], 0u);
          if (n >= r) { bsel = bin; r -= acc0; break; }
          acc0 = n;
        }
        u32 pref = prefix_s[b] | ((u32)bsel << (24 - 8 * level));
        prefix_s[b] = pref;
        rank_s[b] = r;
        if (level == 3) thresh[b] = key2f(pref);
      }
      for (int i = 0; i < 256; ++i) hist[b * 256 + i] = 0;
      if (level == 3) peak_cnt[b] = 0;   // ready for next scale
    }
  }
}

// ---------------------------------------------------------------------------
// K5a: per-(b,c) softmax stats: m = max(masked attn), rZ = 1/sum exp(a-m).
// ---------------------------------------------------------------------------
__global__ void k_softstats(const float* __restrict__ corr, const float* thresh,
                            float2* __restrict__ mZ, int Ls) {
  __shared__ float row[1024];
  __shared__ float red_s[8];
  const int tid = threadIdx.x;
  const int bc = blockIdx.x;
  const int b = bc >> 9;
  const float th = thresh[b];
  const float* src = corr + (size_t)bc * Ls;
  for (int t = tid; t < Ls; t += 256) row[t] = src[t];
  __syncthreads();
  float mx = 0.f;   // zeros always present in attn row -> true max >= 0
  for (int t = tid; t < Ls; t += 256) {
    float v = row[t];
    bool pk = (t >= 1) && (t <= Ls - 2) && (v > row[t - 1]) && (v > row[t + 1]) && (v >= th);
    if (pk) mx = fmaxf(mx, v);
  }
  for (int off = 32; off; off >>= 1) mx = fmaxf(mx, __shfl_down(mx, off, 64));
  if ((tid & 63) == 0) red_s[tid >> 6] = mx;
  __syncthreads();
  float m = fmaxf(fmaxf(red_s[0], red_s[1]), fmaxf(red_s[2], red_s[3]));
  float zs = 0.f;
  for (int t = tid; t < Ls; t += 256) {
    float v = row[t];
    bool pk = (t >= 1) && (t <= Ls - 2) && (v > row[t - 1]) && (v > row[t + 1]) && (v >= th);
    float a = pk ? v : 0.f;
    zs += __expf(a - m);
  }
  for (int off = 32; off; off >>= 1) zs += __shfl_down(zs, off, 64);
  if ((tid & 63) == 0) red_s[4 + (tid >> 6)] = zs;
  __syncthreads();
  if (tid == 0) {
    float Z = red_s[4] + red_s[5] + red_s[6] + red_s[7];
    mZ[bc] = make_float2(m, 1.0f / Z);
  }
}

// ---------------------------------------------------------------------------
// K5b (s=2,4): o_s[b][tau][c] = softmax-weight * pooled v.   Coalesced.
// ---------------------------------------------------------------------------
__global__ void k_apply(const float* __restrict__ corr, const float* __restrict__ V,
                        const float2* __restrict__ mZ, const float* thresh,
                        float* __restrict__ o, int Ls, int s) {
  __shared__ float ct[64][37];
  __shared__ float m_s[64], rz_s[64];
  const int tid = threadIdx.x;
  const int b = blockIdx.z;
  const int c0 = blockIdx.y << 6;
  const int t0 = blockIdx.x << 5;
  {
    const int r0 = tid >> 5, lane = tid & 31;
    for (int rr = r0; rr < 64; rr += 8) {
      const float* src = corr + ((size_t)b * C_ + c0 + rr) * Ls;
      for (int j = lane; j < 34; j += 32) {
        int t = t0 - 1 + j;
        t = max(0, min(t, Ls - 1));
        ct[rr][j] = src[t];
      }
    }
  }
  if (tid < 64) {
    float2 v = mZ[b * C_ + c0 + tid];
    m_s[tid] = v.x; rz_s[tid] = v.y;
  }
  __syncthreads();
  const float th = thresh[b];
  const int cl = tid & 63;
  for (int tl = tid >> 6; tl < 32; tl += 4) {
    int tg = t0 + tl;
    float v = ct[cl][tl + 1];
    bool pk = (tg >= 1) && (tg <= Ls - 2) && (v > ct[cl][tl]) && (v > ct[cl][tl + 2]) && (v >= th);
    float a = pk ? v : 0.f;
    float w = __expf(a - m_s[cl]) * rz_s[cl];
    size_t vb = ((size_t)b * L_ + (size_t)tg * s) * C_ + c0 + cl;
    float vv;
    if (s == 2) vv = (V[vb] + V[vb + C_]) * 0.5f;
    else vv = ((V[vb] + V[vb + C_]) + (V[vb + 2 * C_] + V[vb + 3 * C_])) * 0.25f;
    o[((size_t)b * Ls + tg) * C_ + c0 + cl] = w * vv;
  }
}

// ---------------------------------------------------------------------------
// K5b-final (s=1): out = sw0*w*v + sw1*lerp(o2) + sw2*lerp(o4). Coalesced.
// ---------------------------------------------------------------------------
__global__ void k_apply_final(const float* __restrict__ corr, const float* __restrict__ V,
                              const float2* __restrict__ mZ, const float* thresh,
                              const float* __restrict__ o2, const float* __restrict__ o4,
                              const float* __restrict__ sw, float* __restrict__ out) {
  __shared__ float ct[64][37];
  __shared__ float m_s[64], rz_s[64];
  const int Ls = 1024;
  const int tid = threadIdx.x;
  const int b = blockIdx.z;
  const int c0 = blockIdx.y << 6;
  const int t0 = blockIdx.x << 5;
  {
    const int r0 = tid >> 5, lane = tid & 31;
    for (int rr = r0; rr < 64; rr += 8) {
      const float* src = corr + ((size_t)b * C_ + c0 + rr) * Ls;
      for (int j = lane; j < 34; j += 32) {
        int t = t0 - 1 + j;
        t = max(0, min(t, Ls - 1));
        ct[rr][j] = src[t];
      }
    }
  }
  if (tid < 64) {
    float2 v = mZ[b * C_ + c0 + tid];
    m_s[tid] = v.x; rz_s[tid] = v.y;
  }
  __syncthreads();
  const float th = thresh[b];
  const float sw0 = sw[0], sw1 = sw[1], sw2 = sw[2];
  const int cl = tid & 63;
  for (int tl = tid >> 6; tl < 32; tl += 4) {
    int tg = t0 + tl;
    float v = ct[cl][tl + 1];
    bool pk = (tg >= 1) && (tg <= Ls - 2) && (v > ct[cl][tl]) && (v > ct[cl][tl + 2]) && (v >= th);
    float a = pk ? v : 0.f;
    float w = __expf(a - m_s[cl]) * rz_s[cl];
    float v1 = V[((size_t)b * L_ + tg) * C_ + c0 + cl];
    float r = sw0 * w * v1;
    {
      float srcp = fmaxf((tg + 0.5f) * 0.5f - 0.5f, 0.f);
      int x0 = (int)srcp;
      float lam = srcp - (float)x0;
      int x1 = min(x0 + 1, 511);
      const float* p = o2 + (size_t)b * 512 * C_ + c0 + cl;
      r += sw1 * ((1.f - lam) * p[(size_t)x0 * C_] + lam * p[(size_t)x1 * C_]);
    }
    {
      float srcp = fmaxf((tg + 0.5f) * 0.25f - 0.5f, 0.f);
      int x0 = (int)srcp;
      float lam = srcp - (float)x0;
      int x1 = min(x0 + 1, 255);
      const float* p = o4 + (size_t)b * 256 * C_ + c0 + cl;
      r += sw2 * ((1.f - lam) * p[(size_t)x0 * C_] + lam * p[(size_t)x1 * C_]);
    }
    out[((size_t)b * L_ + tg) * C_ + c0 + cl] = r;
  }
}

// ---------------------------------------------------------------------------
extern "C" void kernel_launch(void* const* d_in, const int* in_sizes, int n_in,
                              void* d_out, int out_size, void* d_ws, size_t ws_size,
                              hipStream_t stream) {
  const float* Q  = (const float*)d_in[0];
  const float* Kk = (const float*)d_in[1];
  const float* V  = (const float*)d_in[2];
  const float* sw = (const float*)d_in[3];
  const float* w1 = (const float*)d_in[4];
  const float* b1 = (const float*)d_in[5];
  const float* w2 = (const float*)d_in[6];
  const float* b2 = (const float*)d_in[7];
  const float* w3 = (const float*)d_in[8];
  const float* b3 = (const float*)d_in[9];
  float* out = (float*)d_out;

  char* ws = (char*)d_ws;
  size_t p = 0;
  auto alloc = [&](size_t n) { char* r = ws + p; p = (p + n + 255) & ~(size_t)255; return r; };
  float*  corr     = (float*)alloc((size_t)B_ * C_ * 1024 * 4);   // 33.5 MB
  float*  o2       = (float*)alloc((size_t)B_ * 512 * C_ * 4);    // 16.8 MB
  float*  o4       = (float*)alloc((size_t)B_ * 256 * C_ * 4);    //  8.4 MB
  u32*    pk_buf   = (u32*)  alloc((size_t)B_ * PK_CAP * 4);      // 16.8 MB
  float*  cm       = (float*)alloc((size_t)B_ * 1024 * 4);
  float2* mZ       = (float2*)alloc((size_t)B_ * C_ * 8);
  double* s1       = (double*)alloc(B_ * 8);
  double* s2       = (double*)alloc(B_ * 8);
  u32*    histA    = (u32*)alloc(B_ * 256 * 4);
  u32*    histB    = (u32*)alloc(B_ * 256 * 4);
  u32*    peak_cnt = (u32*)alloc(B_ * 4);
  u32*    done     = (u32*)alloc(256);
  int*    kvals    = (int*)alloc(B_ * 4);
  int*    rank_s   = (int*)alloc(B_ * 4);
  u32*    prefix_s = (u32*)alloc(B_ * 4);
  u32*    active   = (u32*)alloc(B_ * 4);
  float*  thresh   = (float*)alloc(B_ * 4);

  hipLaunchKernelGGL(k_init, dim3(1), dim3(256), 0, stream,
                     histA, histB, done, peak_cnt, s1, s2);

  const int scales[3] = {4, 2, 1};   // scale 1 last: its epilogue fuses interp
  for (int si = 0; si < 3; ++si) {
    const int s = scales[si];
    const int Ls = 1024 / s;
    hipLaunchKernelGGL(k_corr, dim3(Ls / 128, B_ * H_), dim3(256), 0, stream,
                       Q, Kk, corr, Ls, s);
    hipLaunchKernelGGL(k_stats, dim3(Ls / 256, B_), dim3(256), 0, stream,
                       corr, cm, s1, s2, peak_cnt, histA, pk_buf, Ls);
    hipLaunchKernelGGL(k_mlp, dim3(1), dim3(256), 0, stream,
                       cm, s1, s2, peak_cnt, histA, kvals, rank_s, prefix_s,
                       active, thresh, w1, b1, w2, b2, w3, b3, Ls);
    hipLaunchKernelGGL(k_select, dim3(B_ * NB_SEL), dim3(256), 0, stream,
                       pk_buf, peak_cnt, active, rank_s, prefix_s, histB, done, thresh, 1);
    hipLaunchKernelGGL(k_select, dim3(B_ * NB_SEL), dim3(256), 0, stream,
                       pk_buf, peak_cnt, active, rank_s, prefix_s, histA, done, thresh, 2);
    hipLaunchKernelGGL(k_select, dim3(B_ * NB_SEL), dim3(256), 0, stream,
                       pk_buf, peak_cnt, active, rank_s, prefix_s, histB, done, thresh, 3);
    hipLaunchKernelGGL(k_softstats, dim3(B_ * C_), dim3(256), 0, stream,
                       corr, thresh, mZ, Ls);
    if (s > 1) {
      hipLaunchKernelGGL(k_apply, dim3(Ls / 32, C_ / 64, B_), dim3(256), 0, stream,
                         corr, V, mZ, thresh, (s == 2) ? o2 : o4, Ls, s);
    } else {
      hipLaunchKernelGGL(k_apply_final, dim3(1024 / 32, C_ / 64, B_), dim3(256), 0, stream,
                         corr, V, mZ, thresh, o2, o4, sw, out);
    }
  }
}

// Round 2
// 2579.948 us; speedup vs baseline: 1.9576x; 1.9576x over previous
//
#include <hip/hip_runtime.h>
#include <math.h>

typedef unsigned int u32;
typedef unsigned long long u64;

#define B_ 16
#define L_ 1024
#define H_ 8
#define E_ 64
#define C_ 512            // H_*E_
#define NB_SEL 8          // blocks per batch in radix-select passes
#define PK_CAP 262144     // per-b peak value capacity (C_*511 max = 261632)
#define GCH 8             // channels per k_stats block

__device__ __forceinline__ u32 f2key(float f) {
  u32 u = __float_as_uint(f);
  return (u & 0x80000000u) ? ~u : (u | 0x80000000u);
}
__device__ __forceinline__ float key2f(u32 k) {
  u32 u = (k & 0x80000000u) ? (k ^ 0x80000000u) : ~k;
  return __uint_as_float(u);
}

// ---------------------------------------------------------------------------
// K_init: zero the small control state (ws is re-poisoned 0xAA every launch)
// ---------------------------------------------------------------------------
__global__ void k_init(u32* histA, u32* histB, u32* done, u32* peak_cnt,
                       double* s1, double* s2, float* cm) {
  int tid = threadIdx.x;
  for (int i = tid; i < 16 * 256; i += 256) { histA[i] = 0; histB[i] = 0; }
  for (int i = tid; i < 16 * 1024; i += 256) cm[i] = 0.f;
  if (tid < 48) done[tid] = 0;
  if (tid < 16) { peak_cnt[tid * 16] = 0; s1[tid] = 0.0; s2[tid] = 0.0; }
}

// ---------------------------------------------------------------------------
// K1: circular cross-correlation, fp32 direct.
// corr[b, c=h*64+e, tau] = sum_t q[t]*k[(t-tau) mod Ls], q/k pooled on the fly.
// Block: 256 thr = 64 e-lanes x 4 slots; each thread: 32 consecutive tau.
// Register-rotated k window: per t-step 2 ds_read_b32 + 32 v_fma_f32.
// ---------------------------------------------------------------------------
__launch_bounds__(256, 2)
__global__ void k_corr(const float* __restrict__ Q, const float* __restrict__ K,
                       float* __restrict__ corr, int Ls, int s) {
  __shared__ float qs[64 * 64];     // [t_local][e]
  __shared__ float ks[192 * 64];    // [j][e]; reused as transpose buffer
  const int tid = threadIdx.x;
  const int e = tid & 63, slot = tid >> 6;
  const int slot32 = slot << 5;
  const int tau0 = blockIdx.x << 7;         // *128
  const int bh = blockIdx.y;
  const int b = bh >> 3, h = bh & 7;
  const int Lmask = Ls - 1;
  const size_t base_q = (size_t)b * L_ * C_ + (size_t)h * 64 + e;

  float acc[32];
#pragma unroll
  for (int i = 0; i < 32; ++i) acc[i] = 0.f;
  float w[32];

  const int nchunk = Ls >> 6;
  for (int chunk = 0; chunk < nchunk; ++chunk) {
    const int t0 = chunk << 6;
    if (chunk) __syncthreads();
    // stage q rows (pooled) ------------------------------------------------
    for (int j = slot; j < 64; j += 4) {
      int traw = (t0 + j) * s;
      float v;
      if (s == 1) v = Q[base_q + (size_t)traw * C_];
      else if (s == 2)
        v = (Q[base_q + (size_t)traw * C_] + Q[base_q + (size_t)(traw + 1) * C_]) * 0.5f;
      else
        v = ((Q[base_q + (size_t)traw * C_] + Q[base_q + (size_t)(traw + 1) * C_]) +
             (Q[base_q + (size_t)(traw + 2) * C_] + Q[base_q + (size_t)(traw + 3) * C_])) * 0.25f;
      qs[j * 64 + e] = v;
    }
    // stage k rows (pooled, wrapped) --------------------------------------
    for (int j = slot; j < 192; j += 4) {
      int tk = (t0 - tau0 - 127 + j + 2048) & Lmask;  // 2048 is mult of Ls (256/512/1024)
      int traw = tk * s;
      float v;
      if (s == 1) v = K[base_q + (size_t)traw * C_];
      else if (s == 2)
        v = (K[base_q + (size_t)traw * C_] + K[base_q + (size_t)(traw + 1) * C_]) * 0.5f;
      else
        v = ((K[base_q + (size_t)traw * C_] + K[base_q + (size_t)(traw + 1) * C_]) +
             (K[base_q + (size_t)(traw + 2) * C_] + K[base_q + (size_t)(traw + 3) * C_])) * 0.25f;
      ks[j * 64 + e] = v;
    }
    __syncthreads();
    if (chunk == 0) {
#pragma unroll
      for (int i = 0; i < 32; ++i) w[i] = ks[(127 - slot32 - i) * 64 + e];
    }
#pragma unroll
    for (int j = 0; j < 64; ++j) {
      float qv = qs[j * 64 + e];
#pragma unroll
      for (int i = 0; i < 32; ++i) acc[i] = fmaf(qv, w[i], acc[i]);
#pragma unroll
      for (int i = 31; i > 0; --i) w[i] = w[i - 1];
      w[0] = ks[(j + 128 - slot32) * 64 + e];
    }
  }
  // transpose in LDS, coalesced write (tau-contiguous rows) ----------------
  __syncthreads();
  float* wt = ks;  // 128*65 = 8320 floats <= 12288
#pragma unroll
  for (int i = 0; i < 32; ++i) wt[(slot32 + i) * 65 + e] = acc[i];
  __syncthreads();
  const int to = tid & 127;
  const size_t cbase = ((size_t)b * C_ + (size_t)h * 64) * Ls + tau0 + to;
  for (int cr = tid >> 7; cr < 64; cr += 2)
    corr[cbase + (size_t)cr * Ls] = wt[to * 65 + cr];
}

// ---------------------------------------------------------------------------
// K2: per-b stats (sum, sumsq), cm partials (atomic), peak detection,
// peak-value compaction + level-0 (top 8 bit) histogram.
// Grid: (C_/GCH, B) = 1024 blocks. Block loads GCH contiguous rows to LDS.
// ---------------------------------------------------------------------------
__launch_bounds__(256, 4)
__global__ void k_stats(const float* __restrict__ corr, float* __restrict__ cm,
                        double* s1, double* s2, u32* peak_cnt, u32* histA,
                        u32* pk_buf, int Ls) {
  __shared__ __align__(16) float rows[GCH * 1024];
  __shared__ u32 hist_s[256];
  __shared__ double red_d[8];
  const int tid = threadIdx.x;
  const int b = blockIdx.y;
  const int c0 = blockIdx.x * GCH;
  const int lane = tid & 63;
  hist_s[tid] = 0;
  // bulk-load GCH contiguous rows as float4 (coalesced)
  {
    const float4* src4 = (const float4*)(corr + ((size_t)b * C_ + c0) * Ls);
    float4* dst4 = (float4*)rows;
    const int n4 = GCH * Ls / 4;
    for (int i = tid; i < n4; i += 256) dst4[i] = src4[i];
  }
  __syncthreads();
  const int nt = Ls >> 8;         // taus per thread: 4/2/1
  float cmacc[4] = {0.f, 0.f, 0.f, 0.f};
  double ls1 = 0.0, ls2 = 0.0;
  u32* dst_pk = pk_buf + (size_t)b * PK_CAP;
  for (int g = 0; g < GCH; ++g) {
    const float* row = rows + g * Ls;
    for (int i = 0; i < nt; ++i) {
      int t = tid + (i << 8);
      float v = row[t];
      cmacc[i] += v;
      ls1 += (double)v;
      ls2 += (double)v * (double)v;
      bool pk = (t >= 1) && (t <= Ls - 2) && (v > row[t - 1]) && (v > row[t + 1]);
      u64 mask = __ballot(pk);
      if (mask) {
        int cnt = __popcll(mask);
        u32 base = 0;
        if (lane == 0) base = atomicAdd(&peak_cnt[b * 16], (u32)cnt);
        base = __shfl(base, 0, 64);
        if (pk) {
          u32 key = f2key(v);
          atomicAdd(&hist_s[key >> 24], 1u);
          dst_pk[base + (u32)__popcll(mask & ((1ull << lane) - 1ull))] = key;
        }
      }
    }
  }
  // cm partials: one float atomic per owned tau
  for (int i = 0; i < nt; ++i) {
    int t = tid + (i << 8);
    unsafeAtomicAdd(&cm[b * 1024 + t], cmacc[i]);
  }
  // s1/s2: wave reduce -> block reduce -> one double atomic per block
  for (int off = 32; off; off >>= 1) {
    ls1 += __shfl_down(ls1, off, 64);
    ls2 += __shfl_down(ls2, off, 64);
  }
  if (lane == 0) { red_d[tid >> 6] = ls1; red_d[4 + (tid >> 6)] = ls2; }
  __syncthreads();
  if (tid == 0) {
    unsafeAtomicAdd(&s1[b], red_d[0] + red_d[1] + red_d[2] + red_d[3]);
    unsafeAtomicAdd(&s2[b], red_d[4] + red_d[5] + red_d[6] + red_d[7]);
  }
  if (hist_s[tid]) atomicAdd(&histA[b * 256 + tid], hist_s[tid]);
}

// ---------------------------------------------------------------------------
// K3: pk count from cm, MLP -> kvals, level-0 radix scan, state init, and
// cleanup of s1/s2/histA/cm for reuse. Single block.
// ---------------------------------------------------------------------------
__global__ void k_mlp(float* __restrict__ cm, double* s1, double* s2,
                      const u32* peak_cnt, u32* histA, int* kvals, int* rank_s,
                      u32* prefix_s, u32* active, float* thresh,
                      const float* w1, const float* b1, const float* w2,
                      const float* b2, const float* w3, const float* b3, int Ls) {
  const int tid = threadIdx.x;
  __shared__ int red_i[4];
  __shared__ float energy_s;
  if (tid == 0) {
    double tot = 0.0;
    for (int b = 0; b < 16; ++b) tot += s2[b];
    energy_s = (float)(tot / (16.0 * (double)Ls));
  }
  __syncthreads();
  const float rC = 1.0f / (float)C_;
  for (int b = 0; b < 16; ++b) {
    int cnt = 0;
    for (int t = 1 + tid; t <= Ls - 2; t += 256) {
      float v = cm[b * 1024 + t];
      cnt += (v > cm[b * 1024 + t - 1]) && (v > cm[b * 1024 + t + 1]);
    }
    for (int off = 32; off; off >>= 1) cnt += __shfl_down(cnt, off, 64);
    if ((tid & 63) == 0) red_i[tid >> 6] = cnt;
    __syncthreads();
    if (tid == 0) {
      int pk = red_i[0] + red_i[1] + red_i[2] + red_i[3];
      double N = (double)C_ * (double)Ls;
      double var_d = (s2[b] - s1[b] * s1[b] / N) / (N - 1.0);
      float f0 = energy_s, f1 = (float)var_d, f2 = (float)pk;
      float h1[32];
      for (int j = 0; j < 32; ++j)
        h1[j] = fmaxf(0.f, w1[j * 3] * f0 + w1[j * 3 + 1] * f1 + w1[j * 3 + 2] * f2 + b1[j]);
      float h2[16];
      for (int j = 0; j < 16; ++j) {
        float a = b2[j];
        for (int i = 0; i < 32; ++i) a += w2[j * 32 + i] * h1[i];
        h2[j] = fmaxf(0.f, a);
      }
      float z = b3[0];
      for (int i = 0; i < 16; ++i) z += w3[i] * h2[i];
      float ratio = 1.0f / (1.0f + __expf(-z));
      int kv = (int)(ratio * (float)Ls);
      kv = min(max(kv, 1), Ls);
      kvals[b] = kv;
      int cntb = (int)peak_cnt[b * 16];
      int act = cntb > kv;
      active[b] = (u32)act;
      thresh[b] = -INFINITY;
      if (act) {
        int r = kv, acc0 = 0;
        u32 pref = 0;
        for (int bin = 255; bin >= 0; --bin) {
          int n = acc0 + (int)histA[b * 256 + bin];
          if (n >= r) { pref = (u32)bin << 24; r -= acc0; break; }
          acc0 = n;
        }
        prefix_s[b] = pref;
        rank_s[b] = r;
      }
    }
    __syncthreads();
    histA[b * 256 + tid] = 0;                       // ready for level 2
    for (int t = tid; t < 1024; t += 256) cm[b * 1024 + t] = 0.f;  // next scale
    if (tid == 0) { s1[b] = 0.0; s2[b] = 0.0; }     // ready for next scale
    __syncthreads();
  }
  // NOTE: cm was accumulated 1/C_-unscaled; scaling by rC is folded into the
  // peak comparison being scale-invariant (v > neighbors unaffected). rC kept
  // for clarity; intentionally unused otherwise.
  (void)rC;
}

// ---------------------------------------------------------------------------
// K_sel (levels 1..3): 8-bit radix refinement, ticket-pattern finisher.
// ---------------------------------------------------------------------------
__global__ void k_select(const u32* __restrict__ pk_buf, u32* peak_cnt,
                         const u32* active, int* rank_s, u32* prefix_s,
                         u32* hist, u32* done, float* thresh, int level) {
  const int tid = threadIdx.x;
  const int b = blockIdx.x / NB_SEL;
  const int blk = blockIdx.x % NB_SEL;
  __shared__ u32 hist_s[256];
  hist_s[tid] = 0;
  __syncthreads();
  const int act = (int)active[b];
  const u32 cnt = peak_cnt[b * 16];
  if (act) {
    const u32 pref = prefix_s[b];
    const int hi_sh = 32 - 8 * level;
    const int b_sh = 24 - 8 * level;
    const u32 lo = (u32)(((u64)cnt * (u64)blk) / NB_SEL);
    const u32 hi = (u32)(((u64)cnt * (u64)(blk + 1)) / NB_SEL);
    const u32* src = pk_buf + (size_t)b * PK_CAP;
    for (u32 i = lo + tid; i < hi; i += 256) {
      u32 key = src[i];
      if ((key >> hi_sh) == (pref >> hi_sh))
        atomicAdd(&hist_s[(key >> b_sh) & 255u], 1u);
    }
  }
  __syncthreads();
  if (hist_s[tid]) atomicAdd(&hist[b * 256 + tid], hist_s[tid]);
  __threadfence();
  __syncthreads();
  if (tid == 0) {
    u32 t = atomicAdd(&done[(level - 1) * 16 + b], 1u);
    if (t == NB_SEL - 1) {
      done[(level - 1) * 16 + b] = 0;
      __threadfence();
      if (act) {
        int r = rank_s[b], acc0 = 0, bsel = 0;
        for (int bin = 255; bin >= 0; --bin) {
          int n = acc0 + (int)atomicAdd(&hist[b * 256 + bin], 0u);
          if (n >= r) { bsel = bin; r -= acc0; break; }
          acc0 = n;
        }
        u32 pref = prefix_s[b] | ((u32)bsel << (24 - 8 * level));
        prefix_s[b] = pref;
        rank_s[b] = r;
        if (level == 3) thresh[b] = key2f(pref);
      }
      for (int i = 0; i < 256; ++i) hist[b * 256 + i] = 0;
      if (level == 3) peak_cnt[b * 16] = 0;   // ready for next scale
    }
  }
}

// ---------------------------------------------------------------------------
// K5a: per-(b,c) softmax stats: m = max(masked attn), rZ = 1/sum exp(a-m).
// ---------------------------------------------------------------------------
__global__ void k_softstats(const float* __restrict__ corr, const float* thresh,
                            float2* __restrict__ mZ, int Ls) {
  __shared__ float row[1024];
  __shared__ float red_s[8];
  const int tid = threadIdx.x;
  const int bc = blockIdx.x;
  const int b = bc >> 9;
  const float th = thresh[b];
  const float* src = corr + (size_t)bc * Ls;
  for (int t = tid; t < Ls; t += 256) row[t] = src[t];
  __syncthreads();
  float mx = 0.f;   // zeros always present in attn row -> true max >= 0
  for (int t = tid; t < Ls; t += 256) {
    float v = row[t];
    bool pk = (t >= 1) && (t <= Ls - 2) && (v > row[t - 1]) && (v > row[t + 1]) && (v >= th);
    if (pk) mx = fmaxf(mx, v);
  }
  for (int off = 32; off; off >>= 1) mx = fmaxf(mx, __shfl_down(mx, off, 64));
  if ((tid & 63) == 0) red_s[tid >> 6] = mx;
  __syncthreads();
  float m = fmaxf(fmaxf(red_s[0], red_s[1]), fmaxf(red_s[2], red_s[3]));
  float zs = 0.f;
  for (int t = tid; t < Ls; t += 256) {
    float v = row[t];
    bool pk = (t >= 1) && (t <= Ls - 2) && (v > row[t - 1]) && (v > row[t + 1]) && (v >= th);
    float a = pk ? v : 0.f;
    zs += __expf(a - m);
  }
  for (int off = 32; off; off >>= 1) zs += __shfl_down(zs, off, 64);
  if ((tid & 63) == 0) red_s[4 + (tid >> 6)] = zs;
  __syncthreads();
  if (tid == 0) {
    float Z = red_s[4] + red_s[5] + red_s[6] + red_s[7];
    mZ[bc] = make_float2(m, 1.0f / Z);
  }
}

// ---------------------------------------------------------------------------
// K5b (s=2,4): o_s[b][tau][c] = softmax-weight * pooled v.   Coalesced.
// ---------------------------------------------------------------------------
__global__ void k_apply(const float* __restrict__ corr, const float* __restrict__ V,
                        const float2* __restrict__ mZ, const float* thresh,
                        float* __restrict__ o, int Ls, int s) {
  __shared__ float ct[64][37];
  __shared__ float m_s[64], rz_s[64];
  const int tid = threadIdx.x;
  const int b = blockIdx.z;
  const int c0 = blockIdx.y << 6;
  const int t0 = blockIdx.x << 5;
  {
    const int r0 = tid >> 5, lane = tid & 31;
    for (int rr = r0; rr < 64; rr += 8) {
      const float* src = corr + ((size_t)b * C_ + c0 + rr) * Ls;
      for (int j = lane; j < 34; j += 32) {
        int t = t0 - 1 + j;
        t = max(0, min(t, Ls - 1));
        ct[rr][j] = src[t];
      }
    }
  }
  if (tid < 64) {
    float2 v = mZ[b * C_ + c0 + tid];
    m_s[tid] = v.x; rz_s[tid] = v.y;
  }
  __syncthreads();
  const float th = thresh[b];
  const int cl = tid & 63;
  for (int tl = tid >> 6; tl < 32; tl += 4) {
    int tg = t0 + tl;
    float v = ct[cl][tl + 1];
    bool pk = (tg >= 1) && (tg <= Ls - 2) && (v > ct[cl][tl]) && (v > ct[cl][tl + 2]) && (v >= th);
    float a = pk ? v : 0.f;
    float w = __expf(a - m_s[cl]) * rz_s[cl];
    size_t vb = ((size_t)b * L_ + (size_t)tg * s) * C_ + c0 + cl;
    float vv;
    if (s == 2) vv = (V[vb] + V[vb + C_]) * 0.5f;
    else vv = ((V[vb] + V[vb + C_]) + (V[vb + 2 * C_] + V[vb + 3 * C_])) * 0.25f;
    o[((size_t)b * Ls + tg) * C_ + c0 + cl] = w * vv;
  }
}

// ---------------------------------------------------------------------------
// K5b-final (s=1): out = sw0*w*v + sw1*lerp(o2) + sw2*lerp(o4). Coalesced.
// ---------------------------------------------------------------------------
__global__ void k_apply_final(const float* __restrict__ corr, const float* __restrict__ V,
                              const float2* __restrict__ mZ, const float* thresh,
                              const float* __restrict__ o2, const float* __restrict__ o4,
                              const float* __restrict__ sw, float* __restrict__ out) {
  __shared__ float ct[64][37];
  __shared__ float m_s[64], rz_s[64];
  const int Ls = 1024;
  const int tid = threadIdx.x;
  const int b = blockIdx.z;
  const int c0 = blockIdx.y << 6;
  const int t0 = blockIdx.x << 5;
  {
    const int r0 = tid >> 5, lane = tid & 31;
    for (int rr = r0; rr < 64; rr += 8) {
      const float* src = corr + ((size_t)b * C_ + c0 + rr) * Ls;
      for (int j = lane; j < 34; j += 32) {
        int t = t0 - 1 + j;
        t = max(0, min(t, Ls - 1));
        ct[rr][j] = src[t];
      }
    }
  }
  if (tid < 64) {
    float2 v = mZ[b * C_ + c0 + tid];
    m_s[tid] = v.x; rz_s[tid] = v.y;
  }
  __syncthreads();
  const float th = thresh[b];
  const float sw0 = sw[0], sw1 = sw[1], sw2 = sw[2];
  const int cl = tid & 63;
  for (int tl = tid >> 6; tl < 32; tl += 4) {
    int tg = t0 + tl;
    float v = ct[cl][tl + 1];
    bool pk = (tg >= 1) && (tg <= Ls - 2) && (v > ct[cl][tl]) && (v > ct[cl][tl + 2]) && (v >= th);
    float a = pk ? v : 0.f;
    float w = __expf(a - m_s[cl]) * rz_s[cl];
    float v1 = V[((size_t)b * L_ + tg) * C_ + c0 + cl];
    float r = sw0 * w * v1;
    {
      float srcp = fmaxf((tg + 0.5f) * 0.5f - 0.5f, 0.f);
      int x0 = (int)srcp;
      float lam = srcp - (float)x0;
      int x1 = min(x0 + 1, 511);
      const float* p = o2 + (size_t)b * 512 * C_ + c0 + cl;
      r += sw1 * ((1.f - lam) * p[(size_t)x0 * C_] + lam * p[(size_t)x1 * C_]);
    }
    {
      float srcp = fmaxf((tg + 0.5f) * 0.25f - 0.5f, 0.f);
      int x0 = (int)srcp;
      float lam = srcp - (float)x0;
      int x1 = min(x0 + 1, 255);
      const float* p = o4 + (size_t)b * 256 * C_ + c0 + cl;
      r += sw2 * ((1.f - lam) * p[(size_t)x0 * C_] + lam * p[(size_t)x1 * C_]);
    }
    out[((size_t)b * L_ + tg) * C_ + c0 + cl] = r;
  }
}

// ---------------------------------------------------------------------------
extern "C" void kernel_launch(void* const* d_in, const int* in_sizes, int n_in,
                              void* d_out, int out_size, void* d_ws, size_t ws_size,
                              hipStream_t stream) {
  const float* Q  = (const float*)d_in[0];
  const float* Kk = (const float*)d_in[1];
  const float* V  = (const float*)d_in[2];
  const float* sw = (const float*)d_in[3];
  const float* w1 = (const float*)d_in[4];
  const float* b1 = (const float*)d_in[5];
  const float* w2 = (const float*)d_in[6];
  const float* b2 = (const float*)d_in[7];
  const float* w3 = (const float*)d_in[8];
  const float* b3 = (const float*)d_in[9];
  float* out = (float*)d_out;

  char* ws = (char*)d_ws;
  size_t p = 0;
  auto alloc = [&](size_t n) { char* r = ws + p; p = (p + n + 255) & ~(size_t)255; return r; };
  float*  corr     = (float*)alloc((size_t)B_ * C_ * 1024 * 4);   // 33.5 MB
  float*  o2       = (float*)alloc((size_t)B_ * 512 * C_ * 4);    // 16.8 MB
  float*  o4       = (float*)alloc((size_t)B_ * 256 * C_ * 4);    //  8.4 MB
  u32*    pk_buf   = (u32*)  alloc((size_t)B_ * PK_CAP * 4);      // 16.8 MB
  float*  cm       = (float*)alloc((size_t)B_ * 1024 * 4);
  float2* mZ       = (float2*)alloc((size_t)B_ * C_ * 8);
  double* s1       = (double*)alloc(B_ * 8);
  double* s2       = (double*)alloc(B_ * 8);
  u32*    histA    = (u32*)alloc(B_ * 256 * 4);
  u32*    histB    = (u32*)alloc(B_ * 256 * 4);
  u32*    peak_cnt = (u32*)alloc(B_ * 16 * 4);   // padded: 1 counter / 64B
  u32*    done     = (u32*)alloc(256);
  int*    kvals    = (int*)alloc(B_ * 4);
  int*    rank_s   = (int*)alloc(B_ * 4);
  u32*    prefix_s = (u32*)alloc(B_ * 4);
  u32*    active   = (u32*)alloc(B_ * 4);
  float*  thresh   = (float*)alloc(B_ * 4);

  hipLaunchKernelGGL(k_init, dim3(1), dim3(256), 0, stream,
                     histA, histB, done, peak_cnt, s1, s2, cm);

  const int scales[3] = {4, 2, 1};   // scale 1 last: its epilogue fuses interp
  for (int si = 0; si < 3; ++si) {
    const int s = scales[si];
    const int Ls = 1024 / s;
    hipLaunchKernelGGL(k_corr, dim3(Ls / 128, B_ * H_), dim3(256), 0, stream,
                       Q, Kk, corr, Ls, s);
    hipLaunchKernelGGL(k_stats, dim3(C_ / GCH, B_), dim3(256), 0, stream,
                       corr, cm, s1, s2, peak_cnt, histA, pk_buf, Ls);
    hipLaunchKernelGGL(k_mlp, dim3(1), dim3(256), 0, stream,
                       cm, s1, s2, peak_cnt, histA, kvals, rank_s, prefix_s,
                       active, thresh, w1, b1, w2, b2, w3, b3, Ls);
    hipLaunchKernelGGL(k_select, dim3(B_ * NB_SEL), dim3(256), 0, stream,
                       pk_buf, peak_cnt, active, rank_s, prefix_s, histB, done, thresh, 1);
    hipLaunchKernelGGL(k_select, dim3(B_ * NB_SEL), dim3(256), 0, stream,
                       pk_buf, peak_cnt, active, rank_s, prefix_s, histA, done, thresh, 2);
    hipLaunchKernelGGL(k_select, dim3(B_ * NB_SEL), dim3(256), 0, stream,
                       pk_buf, peak_cnt, active, rank_s, prefix_s, histB, done, thresh, 3);
    hipLaunchKernelGGL(k_softstats, dim3(B_ * C_), dim3(256), 0, stream,
                       corr, thresh, mZ, Ls);
    if (s > 1) {
      hipLaunchKernelGGL(k_apply, dim3(Ls / 32, C_ / 64, B_), dim3(256), 0, stream,
                         corr, V, mZ, thresh, (s == 2) ? o2 : o4, Ls, s);
    } else {
      hipLaunchKernelGGL(k_apply_final, dim3(1024 / 32, C_ / 64, B_), dim3(256), 0, stream,
                         corr, V, mZ, thresh, o2, o4, sw, out);
    }
  }
}

// Round 3
// 1290.481 us; speedup vs baseline: 3.9137x; 1.9992x over previous
//
#include <hip/hip_runtime.h>
#include <math.h>

typedef unsigned int u32;
typedef unsigned long long u64;

#define B_ 16
#define L_ 1024
#define H_ 8
#define E_ 64
#define C_ 512            // H_*E_
#define NB_SEL 8          // blocks per batch in radix-select hist passes
#define PK_CAP 262144     // per-b peak value capacity (C_*511 max = 261632)
#define GCH 8             // channels per k_stats block
#define TC 32             // k_corr time-chunk

__device__ __forceinline__ u32 f2key(float f) {
  u32 u = __float_as_uint(f);
  return (u & 0x80000000u) ? ~u : (u | 0x80000000u);
}
__device__ __forceinline__ float key2f(u32 k) {
  u32 u = (k & 0x80000000u) ? (k ^ 0x80000000u) : ~k;
  return __uint_as_float(u);
}

// ---------------------------------------------------------------------------
// K_init: zero the small control state (ws is re-poisoned 0xAA every launch)
// ---------------------------------------------------------------------------
__global__ void k_init(u32* histA, u32* histB, u32* peak_cnt,
                       double* s1, double* s2, float* cm) {
  int tid = threadIdx.x;
  for (int i = tid; i < 16 * 256; i += 256) { histA[i] = 0; histB[i] = 0; }
  for (int i = tid; i < 16 * 1024; i += 256) cm[i] = 0.f;
  if (tid < 16) { peak_cnt[tid * 16] = 0; s1[tid] = 0.0; s2[tid] = 0.0; }
}

// ---------------------------------------------------------------------------
// K1: circular cross-correlation, fp32 direct, register-tiled (no rotation).
// corr[b, c=h*64+e, tau] = sum_t q[t]*k[(t-tau) mod Ls], q/k pooled on the fly.
// Block: 256 thr = 64 e-lanes x 4 slots; thread owns 32 consecutive taus.
// Per 32-t chunk: stage q(32 rows)+k(160 rows) to LDS as float4, then two
// 16x32 register tiles with a 63-reg k-window -> 1024 static-reg FMAs, 0 movs.
// LDS 48KB -> 3 blocks/CU.
// ---------------------------------------------------------------------------
__device__ __forceinline__ float4 pool_load(const float* gp, int s) {
  float4 v = *(const float4*)gp;
  if (s >= 2) {
    float4 v2 = *(const float4*)(gp + C_);
    v.x += v2.x; v.y += v2.y; v.z += v2.z; v.w += v2.w;
  }
  if (s == 4) {
    float4 v3 = *(const float4*)(gp + 2 * C_);
    float4 v4 = *(const float4*)(gp + 3 * C_);
    v.x += v3.x + v4.x; v.y += v3.y + v4.y;
    v.z += v3.z + v4.z; v.w += v3.w + v4.w;
  }
  float sc = (s == 1) ? 1.f : (s == 2) ? 0.5f : 0.25f;
  v.x *= sc; v.y *= sc; v.z *= sc; v.w *= sc;
  return v;
}

__launch_bounds__(256, 3)
__global__ void k_corr(const float* __restrict__ Q, const float* __restrict__ K,
                       float* __restrict__ corr, int Ls, int s) {
  __shared__ float qs[TC * 64];     // 8KB  [t_local][e]
  __shared__ float ks[160 * 64];    // 40KB [j][e]; reused as transpose buffer
  const int tid = threadIdx.x;
  const int e = tid & 63, slot = tid >> 6;
  const int slot32 = slot << 5;
  const int bh = blockIdx.x;                // bh fastest -> tau-siblings share XCD
  const int tau0 = blockIdx.y << 7;         // *128
  const int b = bh >> 3, h = bh & 7;
  const int Lmask = Ls - 1;
  const size_t gbase = (size_t)b * L_ * C_ + (size_t)h * 64;
  const int l16 = tid & 15;                 // float4 lane within a 64-e row
  const int rbase = tid >> 4;               // 16 rows per staging iteration

  float acc[32];
#pragma unroll
  for (int i = 0; i < 32; ++i) acc[i] = 0.f;

  const int nchunk = Ls / TC;
  for (int chunk = 0; chunk < nchunk; ++chunk) {
    const int t0 = chunk * TC;
    __syncthreads();                        // prev chunk's LDS reads done
    // stage q: TC rows, float4-wide
#pragma unroll
    for (int it = 0; it < TC / 16; ++it) {
      int row = rbase + it * 16;
      int traw = (t0 + row) * s;
      float4 v = pool_load(Q + gbase + (size_t)traw * C_ + l16 * 4, s);
      *(float4*)(qs + row * 64 + l16 * 4) = v;
    }
    // stage k: 160 rows (tau window 128 + chunk 32 - 1), wrapped
#pragma unroll
    for (int it = 0; it < 10; ++it) {
      int row = rbase + it * 16;
      int tk = (t0 - tau0 - 127 + row + 2048) & Lmask;  // 2048 mult of Ls
      float4 v = pool_load(K + gbase + (size_t)tk * s * C_ + l16 * 4, s);
      *(float4*)(ks + row * 64 + l16 * 4) = v;
    }
    __syncthreads();
    // register k-window: km[m] = ks[96 - slot32 + m][e]
    float km[63];
#pragma unroll
    for (int m = 0; m < 47; ++m) km[m] = ks[(96 - slot32 + m) * 64 + e];
#pragma unroll
    for (int jt = 0; jt < 16; ++jt) {       // tile 0: t = t0 + jt
      float qv = qs[jt * 64 + e];
#pragma unroll
      for (int i = 0; i < 32; ++i) acc[i] = fmaf(qv, km[31 + jt - i], acc[i]);
    }
#pragma unroll
    for (int m = 47; m < 63; ++m) km[m] = ks[(96 - slot32 + m) * 64 + e];
#pragma unroll
    for (int jt = 0; jt < 16; ++jt) {       // tile 1: t = t0 + 16 + jt
      float qv = qs[(16 + jt) * 64 + e];
#pragma unroll
      for (int i = 0; i < 32; ++i) acc[i] = fmaf(qv, km[47 + jt - i], acc[i]);
    }
  }
  // transpose in LDS, coalesced write (tau-contiguous rows) ----------------
  __syncthreads();
  float* wt = ks;  // 128*65 = 8320 floats <= 10240
#pragma unroll
  for (int i = 0; i < 32; ++i) wt[(slot32 + i) * 65 + e] = acc[i];
  __syncthreads();
  const int to = tid & 127;
  const size_t cbase = ((size_t)b * C_ + (size_t)h * 64) * Ls + tau0 + to;
  for (int cr = tid >> 7; cr < 64; cr += 2)
    corr[cbase + (size_t)cr * Ls] = wt[to * 65 + cr];
}

// ---------------------------------------------------------------------------
// K2: per-b stats (sum, sumsq), cm partials (atomic), peak detection,
// peak-value compaction + level-0 (top 8 bit) histogram.
// Grid: (C_/GCH, B) = 1024 blocks. Block loads GCH contiguous rows to LDS.
// ---------------------------------------------------------------------------
__launch_bounds__(256, 4)
__global__ void k_stats(const float* __restrict__ corr, float* __restrict__ cm,
                        double* s1, double* s2, u32* peak_cnt, u32* histA,
                        u32* pk_buf, int Ls) {
  __shared__ __align__(16) float rows[GCH * 1024];
  __shared__ u32 hist_s[256];
  __shared__ double red_d[8];
  const int tid = threadIdx.x;
  const int b = blockIdx.y;
  const int c0 = blockIdx.x * GCH;
  const int lane = tid & 63;
  hist_s[tid] = 0;
  {
    const float4* src4 = (const float4*)(corr + ((size_t)b * C_ + c0) * Ls);
    float4* dst4 = (float4*)rows;
    const int n4 = GCH * Ls / 4;
    for (int i = tid; i < n4; i += 256) dst4[i] = src4[i];
  }
  __syncthreads();
  const int nt = Ls >> 8;         // taus per thread: 4/2/1
  float cmacc[4] = {0.f, 0.f, 0.f, 0.f};
  double ls1 = 0.0, ls2 = 0.0;
  u32* dst_pk = pk_buf + (size_t)b * PK_CAP;
  for (int g = 0; g < GCH; ++g) {
    const float* row = rows + g * Ls;
    for (int i = 0; i < nt; ++i) {
      int t = tid + (i << 8);
      float v = row[t];
      cmacc[i] += v;
      ls1 += (double)v;
      ls2 += (double)v * (double)v;
      bool pk = (t >= 1) && (t <= Ls - 2) && (v > row[t - 1]) && (v > row[t + 1]);
      u64 mask = __ballot(pk);
      if (mask) {
        int cnt = __popcll(mask);
        u32 base = 0;
        if (lane == 0) base = atomicAdd(&peak_cnt[b * 16], (u32)cnt);
        base = __shfl(base, 0, 64);
        if (pk) {
          u32 key = f2key(v);
          atomicAdd(&hist_s[key >> 24], 1u);
          dst_pk[base + (u32)__popcll(mask & ((1ull << lane) - 1ull))] = key;
        }
      }
    }
  }
  for (int i = 0; i < nt; ++i) {
    int t = tid + (i << 8);
    unsafeAtomicAdd(&cm[b * 1024 + t], cmacc[i]);
  }
  for (int off = 32; off; off >>= 1) {
    ls1 += __shfl_down(ls1, off, 64);
    ls2 += __shfl_down(ls2, off, 64);
  }
  if (lane == 0) { red_d[tid >> 6] = ls1; red_d[4 + (tid >> 6)] = ls2; }
  __syncthreads();
  if (tid == 0) {
    unsafeAtomicAdd(&s1[b], red_d[0] + red_d[1] + red_d[2] + red_d[3]);
    unsafeAtomicAdd(&s2[b], red_d[4] + red_d[5] + red_d[6] + red_d[7]);
  }
  if (hist_s[tid]) atomicAdd(&histA[b * 256 + tid], hist_s[tid]);
}

// ---------------------------------------------------------------------------
// K3: pk count from cm, MLP -> kvals (16 lanes in parallel, weights in LDS),
// level-0 radix scan via parallel LDS suffix-scan; cleanup for next scale.
// Single block.
// ---------------------------------------------------------------------------
__global__ void k_mlp(float* __restrict__ cm, double* s1, double* s2,
                      const u32* peak_cnt, u32* histA, int* kvals, int* rank_s,
                      u32* prefix_s, u32* active, float* thresh,
                      const float* w1, const float* b1, const float* w2,
                      const float* b2, const float* w3, const float* b3, int Ls) {
  __shared__ float wls[673];       // w1(96) b1(32) w2(512) b2(16) w3(16) b3(1)
  __shared__ float pk_s[16], var_s[16];
  __shared__ float energy_s;
  __shared__ int red_i[4];
  __shared__ u32 cum[256];
  const int tid = threadIdx.x;
  for (int i = tid; i < 96; i += 256) wls[i] = w1[i];
  for (int i = tid; i < 32; i += 256) wls[96 + i] = b1[i];
  for (int i = tid; i < 512; i += 256) wls[128 + i] = w2[i];
  if (tid < 16) wls[640 + tid] = b2[tid];
  if (tid < 16) wls[656 + tid] = w3[tid];
  if (tid == 0) wls[672] = b3[0];
  if (tid == 0) {
    double tot = 0.0;
    for (int b = 0; b < 16; ++b) tot += s2[b];
    energy_s = (float)(tot / (16.0 * (double)Ls));
  }
  // pk count + var per b
  for (int b = 0; b < 16; ++b) {
    __syncthreads();
    int cnt = 0;
    for (int t = 1 + tid; t <= Ls - 2; t += 256) {
      float v = cm[b * 1024 + t];
      cnt += (v > cm[b * 1024 + t - 1]) && (v > cm[b * 1024 + t + 1]);
    }
    for (int off = 32; off; off >>= 1) cnt += __shfl_down(cnt, off, 64);
    if ((tid & 63) == 0) red_i[tid >> 6] = cnt;
    __syncthreads();
    if (tid == 0) {
      pk_s[b] = (float)(red_i[0] + red_i[1] + red_i[2] + red_i[3]);
      double N = (double)C_ * (double)Ls;
      var_s[b] = (float)((s2[b] - s1[b] * s1[b] / N) / (N - 1.0));
    }
  }
  __syncthreads();
  // 16 parallel MLPs (one lane per b), weights broadcast from LDS
  if (tid < 16) {
    const int b = tid;
    float f0 = energy_s, f1 = var_s[b], f2 = pk_s[b];
    float h1[32];
    for (int j = 0; j < 32; ++j)
      h1[j] = fmaxf(0.f, wls[j * 3] * f0 + wls[j * 3 + 1] * f1 + wls[j * 3 + 2] * f2 + wls[96 + j]);
    float h2[16];
    for (int j = 0; j < 16; ++j) {
      float a = wls[640 + j];
      for (int i = 0; i < 32; ++i) a += wls[128 + j * 32 + i] * h1[i];
      h2[j] = fmaxf(0.f, a);
    }
    float z = wls[672];
    for (int i = 0; i < 16; ++i) z += wls[656 + i] * h2[i];
    float ratio = 1.0f / (1.0f + __expf(-z));
    int kv = (int)(ratio * (float)Ls);
    kv = min(max(kv, 1), Ls);
    kvals[b] = kv;
    int cntb = (int)peak_cnt[b * 16];
    active[b] = (u32)(cntb > kv);
    thresh[b] = -INFINITY;
    rank_s[b] = kv;
    prefix_s[b] = 0;
    s1[b] = 0.0; s2[b] = 0.0;           // ready for next scale
  }
  __syncthreads();
  // level-0 radix scan per b: parallel suffix-scan over 256 bins
  for (int b = 0; b < 16; ++b) {
    cum[tid] = histA[b * 256 + tid];
    __syncthreads();
    for (int off = 1; off < 256; off <<= 1) {
      u32 add = (tid + off < 256) ? cum[tid + off] : 0u;
      __syncthreads();
      cum[tid] += add;
      __syncthreads();
    }
    if (active[b]) {
      u32 r = (u32)rank_s[b];
      u32 cnext = (tid == 255) ? 0u : cum[tid + 1];
      if (cum[tid] >= r && cnext < r) {
        prefix_s[b] = (u32)tid << 24;
        rank_s[b] = (int)(r - cnext);
      }
    }
    histA[b * 256 + tid] = 0;           // ready for next scale
    __syncthreads();
  }
  // zero cm for next scale
  for (int i = tid; i < 16 * 1024; i += 256) cm[i] = 0.f;
}

// ---------------------------------------------------------------------------
// K_sel_hist (levels 1..3): histogram of next 8 bits among keys matching
// current prefix. Grid B_*NB_SEL. No finisher — stream order handles it.
// ---------------------------------------------------------------------------
__global__ void k_sel_hist(const u32* __restrict__ pk_buf, const u32* peak_cnt,
                           const u32* active, const u32* prefix_s,
                           u32* hist, int level) {
  const int tid = threadIdx.x;
  const int b = blockIdx.x / NB_SEL;
  const int blk = blockIdx.x % NB_SEL;
  __shared__ u32 hist_s[256];
  hist_s[tid] = 0;
  __syncthreads();
  if (active[b]) {
    const u32 cnt = peak_cnt[b * 16];
    const u32 pref = prefix_s[b];
    const int hi_sh = 32 - 8 * level;
    const int b_sh = 24 - 8 * level;
    const u32 lo = (u32)(((u64)cnt * (u64)blk) / NB_SEL);
    const u32 hi = (u32)(((u64)cnt * (u64)(blk + 1)) / NB_SEL);
    const u32* src = pk_buf + (size_t)b * PK_CAP;
    for (u32 i = lo + tid; i < hi; i += 256) {
      u32 key = src[i];
      if ((key >> hi_sh) == (pref >> hi_sh))
        atomicAdd(&hist_s[(key >> b_sh) & 255u], 1u);
    }
  }
  __syncthreads();
  if (hist_s[tid]) atomicAdd(&hist[b * 256 + tid], hist_s[tid]);
}

// ---------------------------------------------------------------------------
// K_sel_fin (levels 1..3): parallel suffix-scan of hist -> refine prefix/rank.
// Grid: 16 blocks (one per b). Zeroes hist; level3 finalizes thresh+peak_cnt.
// ---------------------------------------------------------------------------
__global__ void k_sel_fin(u32* hist, const u32* active, int* rank_s,
                          u32* prefix_s, u32* peak_cnt, float* thresh, int level) {
  __shared__ u32 cum[256];
  const int b = blockIdx.x;
  const int tid = threadIdx.x;
  cum[tid] = hist[b * 256 + tid];
  __syncthreads();
  for (int off = 1; off < 256; off <<= 1) {
    u32 add = (tid + off < 256) ? cum[tid + off] : 0u;
    __syncthreads();
    cum[tid] += add;
    __syncthreads();
  }
  if (active[b]) {
    u32 r = (u32)rank_s[b];
    u32 cnext = (tid == 255) ? 0u : cum[tid + 1];
    if (cum[tid] >= r && cnext < r) {
      u32 pref = prefix_s[b] | ((u32)tid << (24 - 8 * level));
      prefix_s[b] = pref;
      rank_s[b] = (int)(r - cnext);
      if (level == 3) thresh[b] = key2f(pref);
    }
  }
  hist[b * 256 + tid] = 0;
  if (level == 3 && tid == 0) peak_cnt[b * 16] = 0;   // ready for next scale
}

// ---------------------------------------------------------------------------
// K5a: per-(b,c) softmax stats: m = max(masked attn), rZ = 1/sum exp(a-m).
// ---------------------------------------------------------------------------
__global__ void k_softstats(const float* __restrict__ corr, const float* thresh,
                            float2* __restrict__ mZ, int Ls) {
  __shared__ float row[1024];
  __shared__ float red_s[8];
  const int tid = threadIdx.x;
  const int bc = blockIdx.x;
  const int b = bc >> 9;
  const float th = thresh[b];
  const float* src = corr + (size_t)bc * Ls;
  for (int t = tid; t < Ls; t += 256) row[t] = src[t];
  __syncthreads();
  float mx = 0.f;   // zeros always present in attn row -> true max >= 0
  for (int t = tid; t < Ls; t += 256) {
    float v = row[t];
    bool pk = (t >= 1) && (t <= Ls - 2) && (v > row[t - 1]) && (v > row[t + 1]) && (v >= th);
    if (pk) mx = fmaxf(mx, v);
  }
  for (int off = 32; off; off >>= 1) mx = fmaxf(mx, __shfl_down(mx, off, 64));
  if ((tid & 63) == 0) red_s[tid >> 6] = mx;
  __syncthreads();
  float m = fmaxf(fmaxf(red_s[0], red_s[1]), fmaxf(red_s[2], red_s[3]));
  float zs = 0.f;
  for (int t = tid; t < Ls; t += 256) {
    float v = row[t];
    bool pk = (t >= 1) && (t <= Ls - 2) && (v > row[t - 1]) && (v > row[t + 1]) && (v >= th);
    float a = pk ? v : 0.f;
    zs += __expf(a - m);
  }
  for (int off = 32; off; off >>= 1) zs += __shfl_down(zs, off, 64);
  if ((tid & 63) == 0) red_s[4 + (tid >> 6)] = zs;
  __syncthreads();
  if (tid == 0) {
    float Z = red_s[4] + red_s[5] + red_s[6] + red_s[7];
    mZ[bc] = make_float2(m, 1.0f / Z);
  }
}

// ---------------------------------------------------------------------------
// K5b (s=2,4): o_s[b][tau][c] = softmax-weight * pooled v.   Coalesced.
// ---------------------------------------------------------------------------
__global__ void k_apply(const float* __restrict__ corr, const float* __restrict__ V,
                        const float2* __restrict__ mZ, const float* thresh,
                        float* __restrict__ o, int Ls, int s) {
  __shared__ float ct[64][37];
  __shared__ float m_s[64], rz_s[64];
  const int tid = threadIdx.x;
  const int b = blockIdx.z;
  const int c0 = blockIdx.y << 6;
  const int t0 = blockIdx.x << 5;
  {
    const int r0 = tid >> 5, lane = tid & 31;
    for (int rr = r0; rr < 64; rr += 8) {
      const float* src = corr + ((size_t)b * C_ + c0 + rr) * Ls;
      for (int j = lane; j < 34; j += 32) {
        int t = t0 - 1 + j;
        t = max(0, min(t, Ls - 1));
        ct[rr][j] = src[t];
      }
    }
  }
  if (tid < 64) {
    float2 v = mZ[b * C_ + c0 + tid];
    m_s[tid] = v.x; rz_s[tid] = v.y;
  }
  __syncthreads();
  const float th = thresh[b];
  const int cl = tid & 63;
  for (int tl = tid >> 6; tl < 32; tl += 4) {
    int tg = t0 + tl;
    float v = ct[cl][tl + 1];
    bool pk = (tg >= 1) && (tg <= Ls - 2) && (v > ct[cl][tl]) && (v > ct[cl][tl + 2]) && (v >= th);
    float a = pk ? v : 0.f;
    float w = __expf(a - m_s[cl]) * rz_s[cl];
    size_t vb = ((size_t)b * L_ + (size_t)tg * s) * C_ + c0 + cl;
    float vv;
    if (s == 2) vv = (V[vb] + V[vb + C_]) * 0.5f;
    else vv = ((V[vb] + V[vb + C_]) + (V[vb + 2 * C_] + V[vb + 3 * C_])) * 0.25f;
    o[((size_t)b * Ls + tg) * C_ + c0 + cl] = w * vv;
  }
}

// ---------------------------------------------------------------------------
// K5b-final (s=1): out = sw0*w*v + sw1*lerp(o2) + sw2*lerp(o4). Coalesced.
// ---------------------------------------------------------------------------
__global__ void k_apply_final(const float* __restrict__ corr, const float* __restrict__ V,
                              const float2* __restrict__ mZ, const float* thresh,
                              const float* __restrict__ o2, const float* __restrict__ o4,
                              const float* __restrict__ sw, float* __restrict__ out) {
  __shared__ float ct[64][37];
  __shared__ float m_s[64], rz_s[64];
  const int Ls = 1024;
  const int tid = threadIdx.x;
  const int b = blockIdx.z;
  const int c0 = blockIdx.y << 6;
  const int t0 = blockIdx.x << 5;
  {
    const int r0 = tid >> 5, lane = tid & 31;
    for (int rr = r0; rr < 64; rr += 8) {
      const float* src = corr + ((size_t)b * C_ + c0 + rr) * Ls;
      for (int j = lane; j < 34; j += 32) {
        int t = t0 - 1 + j;
        t = max(0, min(t, Ls - 1));
        ct[rr][j] = src[t];
      }
    }
  }
  if (tid < 64) {
    float2 v = mZ[b * C_ + c0 + tid];
    m_s[tid] = v.x; rz_s[tid] = v.y;
  }
  __syncthreads();
  const float th = thresh[b];
  const float sw0 = sw[0], sw1 = sw[1], sw2 = sw[2];
  const int cl = tid & 63;
  for (int tl = tid >> 6; tl < 32; tl += 4) {
    int tg = t0 + tl;
    float v = ct[cl][tl + 1];
    bool pk = (tg >= 1) && (tg <= Ls - 2) && (v > ct[cl][tl]) && (v > ct[cl][tl + 2]) && (v >= th);
    float a = pk ? v : 0.f;
    float w = __expf(a - m_s[cl]) * rz_s[cl];
    float v1 = V[((size_t)b * L_ + tg) * C_ + c0 + cl];
    float r = sw0 * w * v1;
    {
      float srcp = fmaxf((tg + 0.5f) * 0.5f - 0.5f, 0.f);
      int x0 = (int)srcp;
      float lam = srcp - (float)x0;
      int x1 = min(x0 + 1, 511);
      const float* p = o2 + (size_t)b * 512 * C_ + c0 + cl;
      r += sw1 * ((1.f - lam) * p[(size_t)x0 * C_] + lam * p[(size_t)x1 * C_]);
    }
    {
      float srcp = fmaxf((tg + 0.5f) * 0.25f - 0.5f, 0.f);
      int x0 = (int)srcp;
      float lam = srcp - (float)x0;
      int x1 = min(x0 + 1, 255);
      const float* p = o4 + (size_t)b * 256 * C_ + c0 + cl;
      r += sw2 * ((1.f - lam) * p[(size_t)x0 * C_] + lam * p[(size_t)x1 * C_]);
    }
    out[((size_t)b * L_ + tg) * C_ + c0 + cl] = r;
  }
}

// ---------------------------------------------------------------------------
extern "C" void kernel_launch(void* const* d_in, const int* in_sizes, int n_in,
                              void* d_out, int out_size, void* d_ws, size_t ws_size,
                              hipStream_t stream) {
  const float* Q  = (const float*)d_in[0];
  const float* Kk = (const float*)d_in[1];
  const float* V  = (const float*)d_in[2];
  const float* sw = (const float*)d_in[3];
  const float* w1 = (const float*)d_in[4];
  const float* b1 = (const float*)d_in[5];
  const float* w2 = (const float*)d_in[6];
  const float* b2 = (const float*)d_in[7];
  const float* w3 = (const float*)d_in[8];
  const float* b3 = (const float*)d_in[9];
  float* out = (float*)d_out;

  char* ws = (char*)d_ws;
  size_t p = 0;
  auto alloc = [&](size_t n) { char* r = ws + p; p = (p + n + 255) & ~(size_t)255; return r; };
  float*  corr     = (float*)alloc((size_t)B_ * C_ * 1024 * 4);   // 33.5 MB
  float*  o2       = (float*)alloc((size_t)B_ * 512 * C_ * 4);    // 16.8 MB
  float*  o4       = (float*)alloc((size_t)B_ * 256 * C_ * 4);    //  8.4 MB
  u32*    pk_buf   = (u32*)  alloc((size_t)B_ * PK_CAP * 4);      // 16.8 MB
  float*  cm       = (float*)alloc((size_t)B_ * 1024 * 4);
  float2* mZ       = (float2*)alloc((size_t)B_ * C_ * 8);
  double* s1       = (double*)alloc(B_ * 8);
  double* s2       = (double*)alloc(B_ * 8);
  u32*    histA    = (u32*)alloc(B_ * 256 * 4);
  u32*    histB    = (u32*)alloc(B_ * 256 * 4);
  u32*    peak_cnt = (u32*)alloc(B_ * 16 * 4);   // padded: 1 counter / 64B
  int*    kvals    = (int*)alloc(B_ * 4);
  int*    rank_s   = (int*)alloc(B_ * 4);
  u32*    prefix_s = (u32*)alloc(B_ * 4);
  u32*    active   = (u32*)alloc(B_ * 4);
  float*  thresh   = (float*)alloc(B_ * 4);

  hipLaunchKernelGGL(k_init, dim3(1), dim3(256), 0, stream,
                     histA, histB, peak_cnt, s1, s2, cm);

  const int scales[3] = {4, 2, 1};   // scale 1 last: its epilogue fuses interp
  for (int si = 0; si < 3; ++si) {
    const int s = scales[si];
    const int Ls = 1024 / s;
    hipLaunchKernelGGL(k_corr, dim3(B_ * H_, Ls / 128), dim3(256), 0, stream,
                       Q, Kk, corr, Ls, s);
    hipLaunchKernelGGL(k_stats, dim3(C_ / GCH, B_), dim3(256), 0, stream,
                       corr, cm, s1, s2, peak_cnt, histA, pk_buf, Ls);
    hipLaunchKernelGGL(k_mlp, dim3(1), dim3(256), 0, stream,
                       cm, s1, s2, peak_cnt, histA, kvals, rank_s, prefix_s,
                       active, thresh, w1, b1, w2, b2, w3, b3, Ls);
    for (int level = 1; level <= 3; ++level) {
      hipLaunchKernelGGL(k_sel_hist, dim3(B_ * NB_SEL), dim3(256), 0, stream,
                         pk_buf, peak_cnt, active, prefix_s, histB, level);
      hipLaunchKernelGGL(k_sel_fin, dim3(B_), dim3(256), 0, stream,
                         histB, active, rank_s, prefix_s, peak_cnt, thresh, level);
    }
    hipLaunchKernelGGL(k_softstats, dim3(B_ * C_), dim3(256), 0, stream,
                       corr, thresh, mZ, Ls);
    if (s > 1) {
      hipLaunchKernelGGL(k_apply, dim3(Ls / 32, C_ / 64, B_), dim3(256), 0, stream,
                         corr, V, mZ, thresh, (s == 2) ? o2 : o4, Ls, s);
    } else {
      hipLaunchKernelGGL(k_apply_final, dim3(1024 / 32, C_ / 64, B_), dim3(256), 0, stream,
                         corr, V, mZ, thresh, o2, o4, sw, out);
    }
  }
}

// Round 6
// 1052.599 us; speedup vs baseline: 4.7982x; 1.2260x over previous
//
#include <hip/hip_runtime.h>
#include <math.h>

typedef unsigned int u32;
typedef unsigned long long u64;

#define B_ 16
#define L_ 1024
#define H_ 8
#define E_ 64
#define C_ 512            // H_*E_
#define NB_SEL 8          // blocks per batch in k_sel_hist
#define PK_CAP 262144     // per-b peak key capacity (C_*511 max = 261632)
#define GCH 8             // channels per k_stats block
#define TC 32             // k_corr time-chunk
#define CAPR 160          // k_corr circular K-buffer rows (= 127 + TC + 1)

__device__ __forceinline__ u32 f2key(float f) {
  u32 u = __float_as_uint(f);
  return (u & 0x80000000u) ? ~u : (u | 0x80000000u);
}
__device__ __forceinline__ float key2f(u32 k) {
  u32 u = (k & 0x80000000u) ? (k ^ 0x80000000u) : ~k;
  return __uint_as_float(u);
}

// ---------------------------------------------------------------------------
// K_init: zero the small control state (ws is re-poisoned 0xAA every launch)
// ---------------------------------------------------------------------------
__global__ void k_init(u32* histA, u32* histB, u32* peak_cnt,
                       double* s1, double* s2, float* cm) {
  int tid = threadIdx.x;
  for (int i = tid; i < 16 * 256; i += 256) { histA[i] = 0; histB[i] = 0; }
  for (int i = tid; i < 16 * 1024; i += 256) cm[i] = 0.f;
  if (tid < 16) {
    peak_cnt[tid * 16] = 0;
    s1[tid] = 0.0; s2[tid] = 0.0;
  }
}

// ---------------------------------------------------------------------------
// K1: circular cross-correlation, fp32 direct, register-tiled, circular-K.
// corr[b, c=h*64+e, tau] = sum_t q[t]*k[(t-tau) mod Ls], q/k pooled on the fly.
// Block: 256 thr = 64 e-lanes x 4 slots; thread owns 32 consecutive taus.
// K rows live in a 160-row circular LDS buffer; each chunk stages only 32 new
// rows. km window reads use a wave-uniform wrap branch so the common path is
// contiguous (immediate-offset ds_read).
// ---------------------------------------------------------------------------
__device__ __forceinline__ float4 pool_load(const float* gp, int s) {
  float4 v = *(const float4*)gp;
  if (s >= 2) {
    float4 v2 = *(const float4*)(gp + C_);
    v.x += v2.x; v.y += v2.y; v.z += v2.z; v.w += v2.w;
  }
  if (s == 4) {
    float4 v3 = *(const float4*)(gp + 2 * C_);
    float4 v4 = *(const float4*)(gp + 3 * C_);
    v.x += v3.x + v4.x; v.y += v3.y + v4.y;
    v.z += v3.z + v4.z; v.w += v3.w + v4.w;
  }
  float sc = (s == 1) ? 1.f : (s == 2) ? 0.5f : 0.25f;
  v.x *= sc; v.y *= sc; v.z *= sc; v.w *= sc;
  return v;
}

__launch_bounds__(256, 3)
__global__ void k_corr(const float* __restrict__ Q, const float* __restrict__ K,
                       float* __restrict__ corr, int Ls, int s) {
  __shared__ float qs[TC * 64];       // 8KB  [t_local][e]
  __shared__ float ks[CAPR * 64];     // 40KB circular [p][e]; reused for transpose
  const int tid = threadIdx.x;
  const int e = tid & 63;
  const int slot32 = __builtin_amdgcn_readfirstlane((tid >> 6) << 5);
  const int bh = blockIdx.x;                // bh fastest: tau-sibs share XCD
  const int tau0 = blockIdx.y << 7;         // *128
  const int b = bh >> 3, h = bh & 7;
  const int Lmask = Ls - 1;
  const size_t gbase = (size_t)b * L_ * C_ + (size_t)h * 64;
  const int l16 = tid & 15;                 // float4 lane within a 64-e row
  const int rbase = tid >> 4;               // 16 rows per staging iteration
  const int bp0 = 96 - slot32;              // wave-uniform, in {0,32,64,96}

  float acc[32];
#pragma unroll
  for (int i = 0; i < 32; ++i) acc[i] = 0.f;

  const int nchunk = Ls / TC;
  int cph = 0;                              // (chunk*32) mod 160
  for (int chunk = 0; chunk < nchunk; ++chunk) {
    const int t0 = chunk * TC;
    __syncthreads();                        // prev chunk's LDS reads done
    // stage q: 32 rows, float4-wide
#pragma unroll
    for (int it = 0; it < 2; ++it) {
      int row = rbase + it * 16;
      int traw = (t0 + row) * s;
      float4 v = pool_load(Q + gbase + (size_t)traw * C_ + l16 * 4, s);
      *(float4*)(qs + row * 64 + l16 * 4) = v;
    }
    if (chunk == 0) {
      // initial fill: logical rows l = 0..159, physical p = l
#pragma unroll
      for (int it = 0; it < 10; ++it) {
        int l = rbase + it * 16;
        int tk = (l - tau0 - 127 + 2048) & Lmask;   // 2048 mult of Ls
        float4 v = pool_load(K + gbase + (size_t)tk * s * C_ + l16 * 4, s);
        *(float4*)(ks + l * 64 + l16 * 4) = v;
      }
    } else {
      // stage 32 new rows: l = t0+128 .. t0+159
      int sp = cph + 128; if (sp >= CAPR) sp -= CAPR;
#pragma unroll
      for (int it = 0; it < 2; ++it) {
        int row = rbase + it * 16;
        int l = t0 + 128 + row;
        int tk = (l - tau0 - 127 + 2048) & Lmask;
        int p = sp + row; if (p >= CAPR) p -= CAPR;
        float4 v = pool_load(K + gbase + (size_t)tk * s * C_ + l16 * 4, s);
        *(float4*)(ks + p * 64 + l16 * 4) = v;
      }
    }
    __syncthreads();
    int bp = bp0 + cph; if (bp >= CAPR) bp -= CAPR;   // wave-uniform
    float km[63];
    // phase A: km[0..46]
    if (bp <= CAPR - 47) {
#pragma unroll
      for (int m = 0; m < 47; ++m) km[m] = ks[(bp + m) * 64 + e];
    } else {
#pragma unroll
      for (int m = 0; m < 47; ++m) {
        int p = bp + m; if (p >= CAPR) p -= CAPR;
        km[m] = ks[p * 64 + e];
      }
    }
#pragma unroll
    for (int jt = 0; jt < 16; ++jt) {       // t = t0 + jt
      float qv = qs[jt * 64 + e];
#pragma unroll
      for (int i = 0; i < 32; ++i) acc[i] = fmaf(qv, km[31 + jt - i], acc[i]);
    }
    // phase B: km[47..62]
    if (bp <= CAPR - 63) {
#pragma unroll
      for (int m = 47; m < 63; ++m) km[m] = ks[(bp + m) * 64 + e];
    } else {
#pragma unroll
      for (int m = 47; m < 63; ++m) {
        int p = bp + m; if (p >= CAPR) p -= CAPR;
        km[m] = ks[p * 64 + e];
      }
    }
#pragma unroll
    for (int jt = 16; jt < 32; ++jt) {
      float qv = qs[jt * 64 + e];
#pragma unroll
      for (int i = 0; i < 32; ++i) acc[i] = fmaf(qv, km[31 + jt - i], acc[i]);
    }
    cph += 32; if (cph >= CAPR) cph -= CAPR;
  }
  // transpose in LDS, coalesced write (tau-contiguous rows) ----------------
  __syncthreads();
  float* wt = ks;  // 128*65 = 8320 floats <= 10240
#pragma unroll
  for (int i = 0; i < 32; ++i) wt[(slot32 + i) * 65 + e] = acc[i];
  __syncthreads();
  const int to = tid & 127;
  const size_t cbase = ((size_t)b * C_ + (size_t)h * 64) * Ls + tau0 + to;
  for (int cr = tid >> 7; cr < 64; cr += 2)
    corr[cbase + (size_t)cr * Ls] = wt[to * 65 + cr];
}

// ---------------------------------------------------------------------------
// K2: per-b stats (sum, sumsq), cm partials (unsafe atomic), peak detection,
// compaction (ONE global atomic per block) + level-0 histogram.
// Grid: (C_/GCH, B) = 1024 blocks. Block loads GCH contiguous rows to LDS.
// ---------------------------------------------------------------------------
__launch_bounds__(256, 4)
__global__ void k_stats(const float* __restrict__ corr, float* __restrict__ cm,
                        double* s1, double* s2, u32* peak_cnt, u32* histA,
                        u32* pk_buf, int Ls) {
  __shared__ __align__(16) float rows[GCH * 1024];
  __shared__ u32 hist_s[256];
  __shared__ double red_d[8];
  __shared__ u32 wv[4], wbase[4];
  const int tid = threadIdx.x;
  const int b = blockIdx.y;
  const int c0 = blockIdx.x * GCH;
  const int lane = tid & 63;
  const int wave = tid >> 6;
  hist_s[tid] = 0;
  {
    const float4* src4 = (const float4*)(corr + ((size_t)b * C_ + c0) * Ls);
    float4* dst4 = (float4*)rows;
    const int n4 = GCH * Ls / 4;
    for (int i = tid; i < n4; i += 256) dst4[i] = src4[i];
  }
  __syncthreads();
  const int nt = Ls >> 8;         // taus per thread: 4/2/1
  float cmacc[4] = {0.f, 0.f, 0.f, 0.f};
  double ls1 = 0.0, ls2 = 0.0;
  u32 mycnt = 0;
  // ---- phase 1: stats + peak count + level-0 hist
  for (int g = 0; g < GCH; ++g) {
    const float* row = rows + g * Ls;
    for (int i = 0; i < nt; ++i) {
      int t = tid + (i << 8);
      float v = row[t];
      cmacc[i] += v;
      ls1 += (double)v;
      ls2 += (double)v * (double)v;
      bool pk = (t >= 1) && (t <= Ls - 2) && (v > row[t - 1]) && (v > row[t + 1]);
      if (pk) {
        ++mycnt;
        atomicAdd(&hist_s[f2key(v) >> 24], 1u);
      }
    }
  }
  // block-scan peak counts -> single global atomic for base
  u32 wc = mycnt;
  for (int off = 32; off; off >>= 1) wc += __shfl_down(wc, off, 64);
  if (lane == 0) wv[wave] = wc;
  __syncthreads();
  if (tid == 0) {
    u32 t = 0;
    for (int w = 0; w < 4; ++w) { wbase[w] = t; t += wv[w]; }
    u32 base = atomicAdd(&peak_cnt[b * 16], t);
    for (int w = 0; w < 4; ++w) wbase[w] += base;
  }
  __syncthreads();
  // ---- phase 2: re-detect, compacted write at deterministic offsets
  u32* dst_pk = pk_buf + (size_t)b * PK_CAP;
  u32 off_w = wbase[wave];
  const u64 below = (1ull << lane) - 1ull;
  for (int g = 0; g < GCH; ++g) {
    const float* row = rows + g * Ls;
    for (int i = 0; i < nt; ++i) {
      int t = tid + (i << 8);
      float v = row[t];
      bool pk = (t >= 1) && (t <= Ls - 2) && (v > row[t - 1]) && (v > row[t + 1]);
      u64 mask = __ballot(pk);
      if (pk) dst_pk[off_w + (u32)__popcll(mask & below)] = f2key(v);
      off_w += (u32)__popcll(mask);
    }
  }
  // cm partials: one unsafe float atomic per owned tau
  for (int i = 0; i < nt; ++i) {
    int t = tid + (i << 8);
    unsafeAtomicAdd(&cm[b * 1024 + t], cmacc[i]);
  }
  // s1/s2: wave reduce -> block reduce -> one double atomic per block
  for (int off = 32; off; off >>= 1) {
    ls1 += __shfl_down(ls1, off, 64);
    ls2 += __shfl_down(ls2, off, 64);
  }
  if (lane == 0) { red_d[wave] = ls1; red_d[4 + wave] = ls2; }
  __syncthreads();
  if (tid == 0) {
    unsafeAtomicAdd(&s1[b], red_d[0] + red_d[1] + red_d[2] + red_d[3]);
    unsafeAtomicAdd(&s2[b], red_d[4] + red_d[5] + red_d[6] + red_d[7]);
  }
  if (hist_s[tid]) atomicAdd(&histA[b * 256 + tid], hist_s[tid]);
}

// ---------------------------------------------------------------------------
// K3: pk count from cm (LDS-staged), MLP -> kvals (16 parallel lanes),
// level-0 radix scan (snapshot-then-write: race-free); cleanup for next scale.
// Single block.
// ---------------------------------------------------------------------------
__global__ void k_mlp(float* __restrict__ cm, double* s1, double* s2,
                      const u32* peak_cnt, u32* histA, int* kvals, int* rank_s,
                      u32* prefix_s, u32* active, float* thresh,
                      const float* w1, const float* b1, const float* w2,
                      const float* b2, const float* w3, const float* b3, int Ls) {
  __shared__ float wls[673];       // w1(96) b1(32) w2(512) b2(16) w3(16) b3(1)
  __shared__ float cmrow[1024];
  __shared__ float pk_s[16], var_s[16];
  __shared__ float energy_s;
  __shared__ int red_i[4];
  __shared__ u32 cum[256];
  const int tid = threadIdx.x;
  for (int i = tid; i < 96; i += 256) wls[i] = w1[i];
  for (int i = tid; i < 32; i += 256) wls[96 + i] = b1[i];
  for (int i = tid; i < 512; i += 256) wls[128 + i] = w2[i];
  if (tid < 16) wls[640 + tid] = b2[tid];
  if (tid < 16) wls[656 + tid] = w3[tid];
  if (tid == 0) wls[672] = b3[0];
  if (tid == 0) {
    double tot = 0.0;
    for (int b = 0; b < 16; ++b) tot += s2[b];
    energy_s = (float)(tot / (16.0 * (double)Ls));
  }
  // pk count + var per b (cm row staged in LDS)
  for (int b = 0; b < 16; ++b) {
    __syncthreads();
    for (int i = tid; i < Ls; i += 256) cmrow[i] = cm[b * 1024 + i];
    __syncthreads();
    int cnt = 0;
    for (int t = 1 + tid; t <= Ls - 2; t += 256) {
      float v = cmrow[t];
      cnt += (v > cmrow[t - 1]) && (v > cmrow[t + 1]);
    }
    for (int off = 32; off; off >>= 1) cnt += __shfl_down(cnt, off, 64);
    if ((tid & 63) == 0) red_i[tid >> 6] = cnt;
    __syncthreads();
    if (tid == 0) {
      pk_s[b] = (float)(red_i[0] + red_i[1] + red_i[2] + red_i[3]);
      double N = (double)C_ * (double)Ls;
      var_s[b] = (float)((s2[b] - s1[b] * s1[b] / N) / (N - 1.0));
    }
  }
  __syncthreads();
  // 16 parallel MLPs (one lane per b), weights broadcast from LDS
  if (tid < 16) {
    const int b = tid;
    float f0 = energy_s, f1 = var_s[b], f2 = pk_s[b];
    float h1[32];
    for (int j = 0; j < 32; ++j)
      h1[j] = fmaxf(0.f, wls[j * 3] * f0 + wls[j * 3 + 1] * f1 + wls[j * 3 + 2] * f2 + wls[96 + j]);
    float h2[16];
    for (int j = 0; j < 16; ++j) {
      float a = wls[640 + j];
      for (int i = 0; i < 32; ++i) a += wls[128 + j * 32 + i] * h1[i];
      h2[j] = fmaxf(0.f, a);
    }
    float z = wls[672];
    for (int i = 0; i < 16; ++i) z += wls[656 + i] * h2[i];
    float ratio = 1.0f / (1.0f + __expf(-z));
    int kv = (int)(ratio * (float)Ls);
    kv = min(max(kv, 1), Ls);
    kvals[b] = kv;
    int cntb = (int)peak_cnt[b * 16];
    active[b] = (u32)(cntb > kv);
    thresh[b] = -INFINITY;
    rank_s[b] = kv;
    prefix_s[b] = 0;
    s1[b] = 0.0; s2[b] = 0.0;           // ready for next scale
  }
  __syncthreads();
  // level-0 radix scan per b: parallel suffix-scan over 256 bins
  for (int b = 0; b < 16; ++b) {
    cum[tid] = histA[b * 256 + tid];
    __syncthreads();
    for (int off = 1; off < 256; off <<= 1) {
      u32 add = (tid + off < 256) ? cum[tid + off] : 0u;
      __syncthreads();
      cum[tid] += add;
      __syncthreads();
    }
    // snapshot rank, THEN barrier, THEN single-thread write (race-free)
    u32 act_b = active[b];
    u32 r = act_b ? (u32)rank_s[b] : 0u;
    u32 cc = cum[tid];
    u32 cnext = (tid == 255) ? 0u : cum[tid + 1];
    __syncthreads();
    if (act_b && r > 0 && cc >= r && cnext < r) {
      prefix_s[b] = (u32)tid << 24;
      rank_s[b] = (int)(r - cnext);
    }
    histA[b * 256 + tid] = 0;           // ready for next scale
    __syncthreads();
  }
  // zero cm for next scale
  for (int i = tid; i < 16 * 1024; i += 256) cm[i] = 0.f;
}

// ---------------------------------------------------------------------------
// K_sel_hist (levels 1..3): full pk_buf scan — histogram of next 8 bits among
// keys matching current prefix. Grid B_*NB_SEL. Hist consumed+zeroed by fin.
// ---------------------------------------------------------------------------
__global__ void k_sel_hist(const u32* __restrict__ pk_buf, const u32* peak_cnt,
                           const u32* active, const u32* prefix_s,
                           u32* hist, int level) {
  const int tid = threadIdx.x;
  const int b = blockIdx.x / NB_SEL;
  const int blk = blockIdx.x % NB_SEL;
  __shared__ u32 hist_s[256];
  hist_s[tid] = 0;
  __syncthreads();
  if (active[b]) {
    const u32 cnt = peak_cnt[b * 16];
    const u32 pref = prefix_s[b];
    const int hi_sh = 32 - 8 * level;
    const int b_sh = 24 - 8 * level;
    const u32 lo = (u32)(((u64)cnt * (u64)blk) / NB_SEL);
    const u32 hi = (u32)(((u64)cnt * (u64)(blk + 1)) / NB_SEL);
    const u32* src = pk_buf + (size_t)b * PK_CAP;
    for (u32 i = lo + tid; i < hi; i += 256) {
      u32 key = src[i];
      if ((key >> hi_sh) == (pref >> hi_sh))
        atomicAdd(&hist_s[(key >> b_sh) & 255u], 1u);
    }
  }
  __syncthreads();
  if (hist_s[tid]) atomicAdd(&hist[b * 256 + tid], hist_s[tid]);
}

// ---------------------------------------------------------------------------
// K_sel_fin (levels 1..3): parallel suffix-scan of hist -> refine prefix/rank.
// Snapshot-then-write (race-free). Zeroes hist; level3 finalizes thresh and
// resets peak_cnt for next scale. Grid: 16 blocks.
// ---------------------------------------------------------------------------
__global__ void k_sel_fin(u32* hist, const u32* active, int* rank_s,
                          u32* prefix_s, u32* peak_cnt, float* thresh, int level) {
  __shared__ u32 cum[256];
  const int b = blockIdx.x;
  const int tid = threadIdx.x;
  const int act = (int)active[b];
  cum[tid] = hist[b * 256 + tid];
  hist[b * 256 + tid] = 0;              // ready for next level/scale
  __syncthreads();
  for (int off = 1; off < 256; off <<= 1) {
    u32 add = (tid + off < 256) ? cum[tid + off] : 0u;
    __syncthreads();
    cum[tid] += add;
    __syncthreads();
  }
  // snapshot everything, barrier, then the single selected thread writes
  u32 r = act ? (u32)rank_s[b] : 0u;
  u32 pref = act ? prefix_s[b] : 0u;
  u32 cc = cum[tid];
  u32 cnext = (tid == 255) ? 0u : cum[tid + 1];
  __syncthreads();
  if (act && r > 0 && cc >= r && cnext < r) {
    u32 np = pref | ((u32)tid << (24 - 8 * level));
    prefix_s[b] = np;
    rank_s[b] = (int)(r - cnext);
    if (level == 3) thresh[b] = key2f(np);
  }
  if (level == 3 && tid == 0) peak_cnt[b * 16] = 0;   // ready for next scale
}

// ---------------------------------------------------------------------------
// K5a: per-(b,c) softmax stats: m = max(masked attn), rZ = 1/sum exp(a-m).
// ---------------------------------------------------------------------------
__global__ void k_softstats(const float* __restrict__ corr, const float* thresh,
                            float2* __restrict__ mZ, int Ls) {
  __shared__ float row[1024];
  __shared__ float red_s[8];
  const int tid = threadIdx.x;
  const int bc = blockIdx.x;
  const int b = bc >> 9;
  const float th = thresh[b];
  const float* src = corr + (size_t)bc * Ls;
  for (int t = tid; t < Ls; t += 256) row[t] = src[t];
  __syncthreads();
  float mx = 0.f;   // zeros always present in attn row -> true max >= 0
  for (int t = tid; t < Ls; t += 256) {
    float v = row[t];
    bool pk = (t >= 1) && (t <= Ls - 2) && (v > row[t - 1]) && (v > row[t + 1]) && (v >= th);
    if (pk) mx = fmaxf(mx, v);
  }
  for (int off = 32; off; off >>= 1) mx = fmaxf(mx, __shfl_down(mx, off, 64));
  if ((tid & 63) == 0) red_s[tid >> 6] = mx;
  __syncthreads();
  float m = fmaxf(fmaxf(red_s[0], red_s[1]), fmaxf(red_s[2], red_s[3]));
  float zs = 0.f;
  for (int t = tid; t < Ls; t += 256) {
    float v = row[t];
    bool pk = (t >= 1) && (t <= Ls - 2) && (v > row[t - 1]) && (v > row[t + 1]) && (v >= th);
    float a = pk ? v : 0.f;
    zs += __expf(a - m);
  }
  for (int off = 32; off; off >>= 1) zs += __shfl_down(zs, off, 64);
  if ((tid & 63) == 0) red_s[4 + (tid >> 6)] = zs;
  __syncthreads();
  if (tid == 0) {
    float Z = red_s[4] + red_s[5] + red_s[6] + red_s[7];
    mZ[bc] = make_float2(m, 1.0f / Z);
  }
}

// ---------------------------------------------------------------------------
// K5b (s=2,4): o_s[b][tau][c] = softmax-weight * pooled v. 128-tau tiles.
// ---------------------------------------------------------------------------
__launch_bounds__(256, 4)
__global__ void k_apply(const float* __restrict__ corr, const float* __restrict__ V,
                        const float2* __restrict__ mZ, const float* thresh,
                        float* __restrict__ o, int Ls, int s) {
  __shared__ float ct[64][131];      // col j holds t = t0-1+j (clamped)
  __shared__ float m_s[64], rz_s[64];
  const int tid = threadIdx.x;
  const int b = blockIdx.z;
  const int c0 = blockIdx.y << 6;
  const int t0 = blockIdx.x << 7;
  {
    const int row0 = tid >> 7, jc = tid & 127;
    for (int rr = row0; rr < 64; rr += 2) {
      const float* src = corr + ((size_t)b * C_ + c0 + rr) * Ls;
      for (int j = jc; j < 130; j += 128) {
        int t = t0 - 1 + j;
        t = max(0, min(t, Ls - 1));
        ct[rr][j] = src[t];
      }
    }
  }
  if (tid < 64) {
    float2 v = mZ[b * C_ + c0 + tid];
    m_s[tid] = v.x; rz_s[tid] = v.y;
  }
  __syncthreads();
  const float th = thresh[b];
  const int cl = tid & 63, ts = tid >> 6;
  for (int ii = 0; ii < 32; ++ii) {
    int tl = ts + (ii << 2);
    int tg = t0 + tl;
    float vm = ct[cl][tl], vc = ct[cl][tl + 1], vp = ct[cl][tl + 2];
    bool pk = (tg >= 1) && (tg <= Ls - 2) && (vc > vm) && (vc > vp) && (vc >= th);
    float a = pk ? vc : 0.f;
    float w = __expf(a - m_s[cl]) * rz_s[cl];
    size_t vb = ((size_t)b * L_ + (size_t)tg * s) * C_ + c0 + cl;
    float vv;
    if (s == 2) vv = (V[vb] + V[vb + C_]) * 0.5f;
    else vv = ((V[vb] + V[vb + C_]) + (V[vb + 2 * C_] + V[vb + 3 * C_])) * 0.25f;
    o[((size_t)b * Ls + tg) * C_ + c0 + cl] = w * vv;
  }
}

// ---------------------------------------------------------------------------
// K5b-final (s=1): out = sw0*w*v + sw1*lerp(o2) + sw2*lerp(o4). 128-tau tiles.
// ---------------------------------------------------------------------------
__launch_bounds__(256, 4)
__global__ void k_apply_final(const float* __restrict__ corr, const float* __restrict__ V,
                              const float2* __restrict__ mZ, const float* thresh,
                              const float* __restrict__ o2, const float* __restrict__ o4,
                              const float* __restrict__ sw, float* __restrict__ out) {
  __shared__ float ct[64][131];
  __shared__ float m_s[64], rz_s[64];
  const int Ls = 1024;
  const int tid = threadIdx.x;
  const int b = blockIdx.z;
  const int c0 = blockIdx.y << 6;
  const int t0 = blockIdx.x << 7;
  {
    const int row0 = tid >> 7, jc = tid & 127;
    for (int rr = row0; rr < 64; rr += 2) {
      const float* src = corr + ((size_t)b * C_ + c0 + rr) * Ls;
      for (int j = jc; j < 130; j += 128) {
        int t = t0 - 1 + j;
        t = max(0, min(t, Ls - 1));
        ct[rr][j] = src[t];
      }
    }
  }
  if (tid < 64) {
    float2 v = mZ[b * C_ + c0 + tid];
    m_s[tid] = v.x; rz_s[tid] = v.y;
  }
  __syncthreads();
  const float th = thresh[b];
  const float sw0 = sw[0], sw1 = sw[1], sw2 = sw[2];
  const int cl = tid & 63, ts = tid >> 6;
  for (int ii = 0; ii < 32; ++ii) {
    int tl = ts + (ii << 2);
    int tg = t0 + tl;
    float vm = ct[cl][tl], vc = ct[cl][tl + 1], vp = ct[cl][tl + 2];
    bool pk = (tg >= 1) && (tg <= Ls - 2) && (vc > vm) && (vc > vp) && (vc >= th);
    float a = pk ? vc : 0.f;
    float w = __expf(a - m_s[cl]) * rz_s[cl];
    float v1 = V[((size_t)b * L_ + tg) * C_ + c0 + cl];
    float r = sw0 * w * v1;
    {
      float srcp = fmaxf((tg + 0.5f) * 0.5f - 0.5f, 0.f);
      int x0 = (int)srcp;
      float lam = srcp - (float)x0;
      int x1 = min(x0 + 1, 511);
      const float* p = o2 + (size_t)b * 512 * C_ + c0 + cl;
      r += sw1 * ((1.f - lam) * p[(size_t)x0 * C_] + lam * p[(size_t)x1 * C_]);
    }
    {
      float srcp = fmaxf((tg + 0.5f) * 0.25f - 0.5f, 0.f);
      int x0 = (int)srcp;
      float lam = srcp - (float)x0;
      int x1 = min(x0 + 1, 255);
      const float* p = o4 + (size_t)b * 256 * C_ + c0 + cl;
      r += sw2 * ((1.f - lam) * p[(size_t)x0 * C_] + lam * p[(size_t)x1 * C_]);
    }
    out[((size_t)b * L_ + tg) * C_ + c0 + cl] = r;
  }
}

// ---------------------------------------------------------------------------
extern "C" void kernel_launch(void* const* d_in, const int* in_sizes, int n_in,
                              void* d_out, int out_size, void* d_ws, size_t ws_size,
                              hipStream_t stream) {
  const float* Q  = (const float*)d_in[0];
  const float* Kk = (const float*)d_in[1];
  const float* V  = (const float*)d_in[2];
  const float* sw = (const float*)d_in[3];
  const float* w1 = (const float*)d_in[4];
  const float* b1 = (const float*)d_in[5];
  const float* w2 = (const float*)d_in[6];
  const float* b2 = (const float*)d_in[7];
  const float* w3 = (const float*)d_in[8];
  const float* b3 = (const float*)d_in[9];
  float* out = (float*)d_out;

  char* ws = (char*)d_ws;
  size_t p = 0;
  auto alloc = [&](size_t n) { char* r = ws + p; p = (p + n + 255) & ~(size_t)255; return r; };
  float*  corr     = (float*)alloc((size_t)B_ * C_ * 1024 * 4);   // 33.5 MB
  float*  o2       = (float*)alloc((size_t)B_ * 512 * C_ * 4);    // 16.8 MB
  float*  o4       = (float*)alloc((size_t)B_ * 256 * C_ * 4);    //  8.4 MB
  u32*    pk_buf   = (u32*)  alloc((size_t)B_ * PK_CAP * 4);      // 16.8 MB
  float*  cm       = (float*)alloc((size_t)B_ * 1024 * 4);
  float2* mZ       = (float2*)alloc((size_t)B_ * C_ * 8);
  double* s1       = (double*)alloc(B_ * 8);
  double* s2       = (double*)alloc(B_ * 8);
  u32*    histA    = (u32*)alloc(B_ * 256 * 4);
  u32*    histB    = (u32*)alloc(B_ * 256 * 4);
  u32*    peak_cnt = (u32*)alloc(B_ * 16 * 4);   // padded: 1 counter / 64B
  int*    kvals    = (int*)alloc(B_ * 4);
  int*    rank_s   = (int*)alloc(B_ * 4);
  u32*    prefix_s = (u32*)alloc(B_ * 4);
  u32*    active   = (u32*)alloc(B_ * 4);
  float*  thresh   = (float*)alloc(B_ * 4);

  hipLaunchKernelGGL(k_init, dim3(1), dim3(256), 0, stream,
                     histA, histB, peak_cnt, s1, s2, cm);

  const int scales[3] = {4, 2, 1};   // scale 1 last: its epilogue fuses interp
  for (int si = 0; si < 3; ++si) {
    const int s = scales[si];
    const int Ls = 1024 / s;
    hipLaunchKernelGGL(k_corr, dim3(B_ * H_, Ls / 128), dim3(256), 0, stream,
                       Q, Kk, corr, Ls, s);
    hipLaunchKernelGGL(k_stats, dim3(C_ / GCH, B_), dim3(256), 0, stream,
                       corr, cm, s1, s2, peak_cnt, histA, pk_buf, Ls);
    hipLaunchKernelGGL(k_mlp, dim3(1), dim3(256), 0, stream,
                       cm, s1, s2, peak_cnt, histA, kvals, rank_s, prefix_s,
                       active, thresh, w1, b1, w2, b2, w3, b3, Ls);
    for (int level = 1; level <= 3; ++level) {
      hipLaunchKernelGGL(k_sel_hist, dim3(B_ * NB_SEL), dim3(256), 0, stream,
                         pk_buf, peak_cnt, active, prefix_s, histB, level);
      hipLaunchKernelGGL(k_sel_fin, dim3(B_), dim3(256), 0, stream,
                         histB, active, rank_s, prefix_s, peak_cnt, thresh, level);
    }
    hipLaunchKernelGGL(k_softstats, dim3(B_ * C_), dim3(256), 0, stream,
                       corr, thresh, mZ, Ls);
    if (s > 1) {
      hipLaunchKernelGGL(k_apply, dim3(Ls / 128, C_ / 64, B_), dim3(256), 0, stream,
                         corr, V, mZ, thresh, (s == 2) ? o2 : o4, Ls, s);
    } else {
      hipLaunchKernelGGL(k_apply_final, dim3(1024 / 128, C_ / 64, B_), dim3(256), 0, stream,
                         corr, V, mZ, thresh, o2, o4, sw, out);
    }
  }
}

// Round 7
// 807.941 us; speedup vs baseline: 6.2511x; 1.3028x over previous
//
#include <hip/hip_runtime.h>
#include <math.h>

typedef unsigned int u32;
typedef unsigned long long u64;

#define B_ 16
#define L_ 1024
#define H_ 8
#define E_ 64
#define C_ 512            // H_*E_
#define NB_SEL 8          // blocks per (scale,b) in k_sel
#define GCH 8             // channels per k_stats block
#define TC 32             // k_corr time-chunk
#define CAPR 160          // k_corr circular K-buffer rows (= 127 + TC + 1)

// scale indexing: sidx 0 -> s=1 (Ls=1024), 1 -> s=2 (512), 2 -> s=4 (256)
__device__ __forceinline__ size_t co(int sidx) {       // corr elem offset
  return sidx == 0 ? 0u : (sidx == 1 ? 8388608u : 12582912u);
}
__device__ __forceinline__ u32 pk_off(int sidx) {      // pk elem offset in o-region
  return sidx == 0 ? 0u : (sidx == 1 ? 3211264u : 4816896u);
}
__device__ __forceinline__ u32 pk_cap(int sidx) { return 200704u >> sidx; }

__device__ __forceinline__ u32 f2key(float f) {
  u32 u = __float_as_uint(f);
  return (u & 0x80000000u) ? ~u : (u | 0x80000000u);
}
__device__ __forceinline__ float key2f(u32 k) {
  u32 u = (k & 0x80000000u) ? (k ^ 0x80000000u) : ~k;
  return __uint_as_float(u);
}

// ---------------------------------------------------------------------------
// K_init: zero control state once (single-pass pipeline -> no mid-run resets)
// ---------------------------------------------------------------------------
__global__ void k_init(u32* histA, u32* histB, u32* peak_cnt, u32* done,
                       double* s1, double* s2, float* cm) {
  const int gid = blockIdx.x * 256 + threadIdx.x;
  const int gs = gridDim.x * 256;
  for (int i = gid; i < 3 * 16 * 256; i += gs) { histA[i] = 0; histB[i] = 0; }
  for (int i = gid; i < 3 * 16 * 1024; i += gs) cm[i] = 0.f;
  for (int i = gid; i < 3 * 16 * 16; i += gs) peak_cnt[i] = 0;
  for (int i = gid; i < 144; i += gs) done[i] = 0;
  for (int i = gid; i < 48; i += gs) { s1[i] = 0.0; s2[i] = 0.0; }
}

// ---------------------------------------------------------------------------
// K1: circular cross-correlation, fp32 direct, register-tiled, circular-K,
// templated on scale S. S==1 adds register-prefetch software pipelining:
// prefetch for chunk+1 issues AFTER the compute barrier so the barrier's
// vmcnt(0) drain hits already-complete loads; global latency hides under the
// 2048-cycle FMA section.
// ---------------------------------------------------------------------------
template<int S>
__device__ __forceinline__ float4 pool_load(const float* gp) {
  float4 v = *(const float4*)gp;
  if constexpr (S >= 2) {
    float4 v2 = *(const float4*)(gp + C_);
    v.x += v2.x; v.y += v2.y; v.z += v2.z; v.w += v2.w;
  }
  if constexpr (S == 4) {
    float4 v3 = *(const float4*)(gp + 2 * C_);
    float4 v4 = *(const float4*)(gp + 3 * C_);
    v.x += v3.x + v4.x; v.y += v3.y + v4.y;
    v.z += v3.z + v4.z; v.w += v3.w + v4.w;
  }
  constexpr float sc = (S == 1) ? 1.f : (S == 2) ? 0.5f : 0.25f;
  if constexpr (S >= 2) { v.x *= sc; v.y *= sc; v.z *= sc; v.w *= sc; }
  return v;
}

template<int S>
__launch_bounds__(256, 3)
__global__ void k_corr(const float* __restrict__ Q, const float* __restrict__ K,
                       float* __restrict__ corr) {
  constexpr int LS = 1024 / S;
  constexpr int LMASK = LS - 1;
  constexpr int NCHUNK = LS / TC;
  __shared__ float qs[TC * 64];       // 8KB  [t_local][e]
  __shared__ float ks[CAPR * 64];     // 40KB circular [p][e]; reused for transpose
  const int tid = threadIdx.x;
  const int e = tid & 63;
  const int slot32 = __builtin_amdgcn_readfirstlane((tid >> 6) << 5);
  const int bh = blockIdx.x;
  const int tau0 = blockIdx.y << 7;         // *128
  const int b = bh >> 3, h = bh & 7;
  const size_t gbase = (size_t)b * L_ * C_ + (size_t)h * 64;
  const int l16 = tid & 15;                 // float4 lane within a 64-e row
  const int rbase = tid >> 4;               // 16 rows per staging iteration
  const int bp0 = 96 - slot32;              // wave-uniform, in {0,32,64,96}

  float acc[32];
#pragma unroll
  for (int i = 0; i < 32; ++i) acc[i] = 0.f;

  float4 pq0, pq1, pk0, pk1;                // S==1 prefetch registers
  if constexpr (S == 1) {
    pq0 = *(const float4*)(Q + gbase + (size_t)rbase * C_ + l16 * 4);
    pq1 = *(const float4*)(Q + gbase + (size_t)(rbase + 16) * C_ + l16 * 4);
  }

  int cph = 0;                              // (chunk*32) mod 160
  for (int chunk = 0; chunk < NCHUNK; ++chunk) {
    const int t0 = chunk * TC;
    __syncthreads();                        // prev chunk's LDS reads done
    if constexpr (S == 1) {
      *(float4*)(qs + rbase * 64 + l16 * 4) = pq0;
      *(float4*)(qs + (rbase + 16) * 64 + l16 * 4) = pq1;
      if (chunk == 0) {
        // initial K fill: logical rows 0..159, physical p = l
#pragma unroll
        for (int it = 0; it < 10; ++it) {
          int l = rbase + it * 16;
          int tk = (l - tau0 - 127 + 2048) & LMASK;
          *(float4*)(ks + l * 64 + l16 * 4) =
              *(const float4*)(K + gbase + (size_t)tk * C_ + l16 * 4);
        }
      } else {
        int sp = cph + 128; if (sp >= CAPR) sp -= CAPR;
        int p0 = sp + rbase;      if (p0 >= CAPR) p0 -= CAPR;
        int p1 = sp + rbase + 16; if (p1 >= CAPR) p1 -= CAPR;
        *(float4*)(ks + p0 * 64 + l16 * 4) = pk0;
        *(float4*)(ks + p1 * 64 + l16 * 4) = pk1;
      }
      __syncthreads();
      if (chunk + 1 < NCHUNK) {             // prefetch next chunk
        int t0n = t0 + TC;
        pq0 = *(const float4*)(Q + gbase + (size_t)(t0n + rbase) * C_ + l16 * 4);
        pq1 = *(const float4*)(Q + gbase + (size_t)(t0n + rbase + 16) * C_ + l16 * 4);
        int l0 = t0n + 128 + rbase;
        int tk0 = (l0 - tau0 - 127 + 2048) & LMASK;
        int tk1 = (l0 + 16 - tau0 - 127 + 2048) & LMASK;
        pk0 = *(const float4*)(K + gbase + (size_t)tk0 * C_ + l16 * 4);
        pk1 = *(const float4*)(K + gbase + (size_t)tk1 * C_ + l16 * 4);
      }
    } else {
      // stage q: 32 rows
#pragma unroll
      for (int it = 0; it < 2; ++it) {
        int row = rbase + it * 16;
        int traw = (t0 + row) * S;
        float4 v = pool_load<S>(Q + gbase + (size_t)traw * C_ + l16 * 4);
        *(float4*)(qs + row * 64 + l16 * 4) = v;
      }
      if (chunk == 0) {
#pragma unroll
        for (int it = 0; it < 10; ++it) {
          int l = rbase + it * 16;
          int tk = (l - tau0 - 127 + 2048) & LMASK;
          float4 v = pool_load<S>(K + gbase + (size_t)tk * S * C_ + l16 * 4);
          *(float4*)(ks + l * 64 + l16 * 4) = v;
        }
      } else {
        int sp = cph + 128; if (sp >= CAPR) sp -= CAPR;
#pragma unroll
        for (int it = 0; it < 2; ++it) {
          int row = rbase + it * 16;
          int l = t0 + 128 + row;
          int tk = (l - tau0 - 127 + 2048) & LMASK;
          int p = sp + row; if (p >= CAPR) p -= CAPR;
          float4 v = pool_load<S>(K + gbase + (size_t)tk * S * C_ + l16 * 4);
          *(float4*)(ks + p * 64 + l16 * 4) = v;
        }
      }
      __syncthreads();
    }
    // ---- compute: two 16x32 register tiles over a 63-reg k-window
    int bp = bp0 + cph; if (bp >= CAPR) bp -= CAPR;   // wave-uniform
    float km[63];
    if (bp <= CAPR - 47) {
#pragma unroll
      for (int m = 0; m < 47; ++m) km[m] = ks[(bp + m) * 64 + e];
    } else {
#pragma unroll
      for (int m = 0; m < 47; ++m) {
        int p = bp + m; if (p >= CAPR) p -= CAPR;
        km[m] = ks[p * 64 + e];
      }
    }
#pragma unroll
    for (int jt = 0; jt < 16; ++jt) {
      float qv = qs[jt * 64 + e];
#pragma unroll
      for (int i = 0; i < 32; ++i) acc[i] = fmaf(qv, km[31 + jt - i], acc[i]);
    }
    if (bp <= CAPR - 63) {
#pragma unroll
      for (int m = 47; m < 63; ++m) km[m] = ks[(bp + m) * 64 + e];
    } else {
#pragma unroll
      for (int m = 47; m < 63; ++m) {
        int p = bp + m; if (p >= CAPR) p -= CAPR;
        km[m] = ks[p * 64 + e];
      }
    }
#pragma unroll
    for (int jt = 16; jt < 32; ++jt) {
      float qv = qs[jt * 64 + e];
#pragma unroll
      for (int i = 0; i < 32; ++i) acc[i] = fmaf(qv, km[31 + jt - i], acc[i]);
    }
    cph += 32; if (cph >= CAPR) cph -= CAPR;
  }
  // transpose in LDS, coalesced write (tau-contiguous rows) ----------------
  __syncthreads();
  float* wt = ks;  // 128*65 = 8320 floats <= 10240
#pragma unroll
  for (int i = 0; i < 32; ++i) wt[(slot32 + i) * 65 + e] = acc[i];
  __syncthreads();
  const int to = tid & 127;
  const size_t cbase = ((size_t)b * C_ + (size_t)h * 64) * LS + tau0 + to;
  for (int cr = tid >> 7; cr < 64; cr += 2)
    corr[cbase + (size_t)cr * LS] = wt[to * 65 + cr];
}

// ---------------------------------------------------------------------------
// K2 (merged scales): per-(scale,b) stats, cm partials, peak detect +
// compaction (one global atomic per block) + level-0 histogram.
// Grid: (C_/GCH, B, 3).
// ---------------------------------------------------------------------------
__launch_bounds__(256, 4)
__global__ void k_stats(const float* __restrict__ corrbase, float* __restrict__ cm,
                        double* s1, double* s2, u32* peak_cnt, u32* histA,
                        u32* pkbase) {
  __shared__ __align__(16) float rows[GCH * 1024];
  __shared__ u32 hist_s[256];
  __shared__ double red_d[8];
  __shared__ u32 wv[4], wbase[4];
  const int tid = threadIdx.x;
  const int sidx = blockIdx.z;
  const int b = blockIdx.y;
  const int sb = sidx * 16 + b;
  const int Ls = 1024 >> sidx;
  const int c0 = blockIdx.x * GCH;
  const int lane = tid & 63;
  const int wave = tid >> 6;
  hist_s[tid] = 0;
  {
    const float4* src4 =
        (const float4*)(corrbase + co(sidx) + ((size_t)b * C_ + c0) * Ls);
    float4* dst4 = (float4*)rows;
    const int n4 = GCH * Ls / 4;
    for (int i = tid; i < n4; i += 256) dst4[i] = src4[i];
  }
  __syncthreads();
  const int nt = Ls >> 8;         // taus per thread: 4/2/1
  float cmacc[4] = {0.f, 0.f, 0.f, 0.f};
  double ls1 = 0.0, ls2 = 0.0;
  u32 mycnt = 0;
  // ---- phase 1: stats + peak count + level-0 hist
  for (int g = 0; g < GCH; ++g) {
    const float* row = rows + g * Ls;
    for (int i = 0; i < nt; ++i) {
      int t = tid + (i << 8);
      float v = row[t];
      cmacc[i] += v;
      ls1 += (double)v;
      ls2 += (double)v * (double)v;
      bool pk = (t >= 1) && (t <= Ls - 2) && (v > row[t - 1]) && (v > row[t + 1]);
      if (pk) {
        ++mycnt;
        atomicAdd(&hist_s[f2key(v) >> 24], 1u);
      }
    }
  }
  // block-scan peak counts -> single global atomic for base
  u32 wc = mycnt;
  for (int off = 32; off; off >>= 1) wc += __shfl_down(wc, off, 64);
  if (lane == 0) wv[wave] = wc;
  __syncthreads();
  if (tid == 0) {
    u32 t = 0;
    for (int w = 0; w < 4; ++w) { wbase[w] = t; t += wv[w]; }
    u32 base = atomicAdd(&peak_cnt[sb * 16], t);
    for (int w = 0; w < 4; ++w) wbase[w] += base;
  }
  __syncthreads();
  // ---- phase 2: re-detect, compacted write at deterministic offsets
  const u32 cap = pk_cap(sidx);
  u32* dst_pk = pkbase + pk_off(sidx) + (u32)b * cap;
  u32 off_w = wbase[wave];
  const u64 below = (1ull << lane) - 1ull;
  for (int g = 0; g < GCH; ++g) {
    const float* row = rows + g * Ls;
    for (int i = 0; i < nt; ++i) {
      int t = tid + (i << 8);
      float v = row[t];
      bool pk = (t >= 1) && (t <= Ls - 2) && (v > row[t - 1]) && (v > row[t + 1]);
      u64 mask = __ballot(pk);
      if (pk) {
        u32 idx = off_w + (u32)__popcll(mask & below);
        if (idx < cap) dst_pk[idx] = f2key(v);
      }
      off_w += (u32)__popcll(mask);
    }
  }
  // cm partials: one unsafe float atomic per owned tau
  for (int i = 0; i < nt; ++i) {
    int t = tid + (i << 8);
    unsafeAtomicAdd(&cm[sb * 1024 + t], cmacc[i]);
  }
  // s1/s2: wave reduce -> block reduce -> one double atomic per block
  for (int off = 32; off; off >>= 1) {
    ls1 += __shfl_down(ls1, off, 64);
    ls2 += __shfl_down(ls2, off, 64);
  }
  if (lane == 0) { red_d[wave] = ls1; red_d[4 + wave] = ls2; }
  __syncthreads();
  if (tid == 0) {
    unsafeAtomicAdd(&s1[sb], red_d[0] + red_d[1] + red_d[2] + red_d[3]);
    unsafeAtomicAdd(&s2[sb], red_d[4] + red_d[5] + red_d[6] + red_d[7]);
  }
  if (hist_s[tid]) atomicAdd(&histA[sb * 256 + tid], hist_s[tid]);
}

// ---------------------------------------------------------------------------
// K3 (merged): one block per (scale,b). cm pk-count, MLP -> kvals, level-0
// radix scan (snapshot-then-write). Energy computed redundantly per block.
// ---------------------------------------------------------------------------
__global__ void k_mlp(const float* __restrict__ cm, const double* s1,
                      const double* s2, const u32* peak_cnt, const u32* histA,
                      int* rank_s, u32* prefix_s, u32* active, float* thresh,
                      const float* w1, const float* b1, const float* w2,
                      const float* b2, const float* w3, const float* b3) {
  __shared__ float wls[673];       // w1(96) b1(32) w2(512) b2(16) w3(16) b3(1)
  __shared__ float cmrow[1024];
  __shared__ int red_i[4];
  __shared__ u32 cum[256];
  const int tid = threadIdx.x;
  const int sb = blockIdx.x;
  const int sidx = sb >> 4;
  const int Ls = 1024 >> sidx;
  for (int i = tid; i < 96; i += 256) wls[i] = w1[i];
  for (int i = tid; i < 32; i += 256) wls[96 + i] = b1[i];
  for (int i = tid; i < 512; i += 256) wls[128 + i] = w2[i];
  if (tid < 16) wls[640 + tid] = b2[tid];
  if (tid < 16) wls[656 + tid] = w3[tid];
  if (tid == 0) wls[672] = b3[0];
  for (int i = tid; i < Ls; i += 256) cmrow[i] = cm[sb * 1024 + i];
  __syncthreads();
  int cnt = 0;
  for (int t = 1 + tid; t <= Ls - 2; t += 256) {
    float v = cmrow[t];
    cnt += (v > cmrow[t - 1]) && (v > cmrow[t + 1]);
  }
  for (int off = 32; off; off >>= 1) cnt += __shfl_down(cnt, off, 64);
  if ((tid & 63) == 0) red_i[tid >> 6] = cnt;
  __syncthreads();
  if (tid == 0) {
    double tot = 0.0;
    for (int j = 0; j < 16; ++j) tot += s2[sidx * 16 + j];
    float f0 = (float)(tot / (16.0 * (double)Ls));
    double N = (double)C_ * (double)Ls;
    float f1 = (float)((s2[sb] - s1[sb] * s1[sb] / N) / (N - 1.0));
    float f2 = (float)(red_i[0] + red_i[1] + red_i[2] + red_i[3]);
    float h1[32];
    for (int j = 0; j < 32; ++j)
      h1[j] = fmaxf(0.f, wls[j * 3] * f0 + wls[j * 3 + 1] * f1 + wls[j * 3 + 2] * f2 + wls[96 + j]);
    float h2[16];
    for (int j = 0; j < 16; ++j) {
      float a = wls[640 + j];
      for (int i = 0; i < 32; ++i) a += wls[128 + j * 32 + i] * h1[i];
      h2[j] = fmaxf(0.f, a);
    }
    float z = wls[672];
    for (int i = 0; i < 16; ++i) z += wls[656 + i] * h2[i];
    float ratio = 1.0f / (1.0f + __expf(-z));
    int kv = (int)(ratio * (float)Ls);
    kv = min(max(kv, 1), Ls);
    int cntb = (int)peak_cnt[sb * 16];
    active[sb] = (u32)(cntb > kv);
    thresh[sb] = -INFINITY;
    rank_s[sb] = kv;
    prefix_s[sb] = 0;
  }
  __syncthreads();
  // level-0 radix scan: parallel suffix-scan over 256 bins
  cum[tid] = histA[sb * 256 + tid];
  __syncthreads();
  for (int off = 1; off < 256; off <<= 1) {
    u32 add = (tid + off < 256) ? cum[tid + off] : 0u;
    __syncthreads();
    cum[tid] += add;
    __syncthreads();
  }
  u32 act_b = active[sb];
  u32 r = act_b ? (u32)rank_s[sb] : 0u;
  u32 cc = cum[tid];
  u32 cnext = (tid == 255) ? 0u : cum[tid + 1];
  __syncthreads();          // all snapshots done before any write
  if (act_b && r > 0 && cc >= r && cnext < r) {
    prefix_s[sb] = (u32)tid << 24;
    rank_s[sb] = (int)(r - cnext);
  }
}

// ---------------------------------------------------------------------------
// K_sel (levels 1..3): full key scan, LDS->global hist, ticket finisher does
// the parallel suffix-scan + snapshot-write refine. Grid: 3*16*NB_SEL.
// ---------------------------------------------------------------------------
__global__ void k_sel(const u32* __restrict__ pkbase, const u32* peak_cnt,
                      const u32* active, int* rank_s, u32* prefix_s,
                      u32* hist, u32* done, float* thresh, int level) {
  __shared__ u32 hist_s[256];
  __shared__ u32 cum[256];
  __shared__ u32 islast;
  const int tid = threadIdx.x;
  const int sb = blockIdx.x / NB_SEL;
  const int blk = blockIdx.x % NB_SEL;
  const int sidx = sb >> 4;
  hist_s[tid] = 0;
  if (tid == 0) islast = 0;
  __syncthreads();
  const int act = (int)active[sb];
  const u32 cap = pk_cap(sidx);
  u32 cnt = peak_cnt[sb * 16];
  if (cnt > cap) cnt = cap;
  if (act) {
    const u32 pref = prefix_s[sb];
    const int hi_sh = 32 - 8 * level;
    const int b_sh = 24 - 8 * level;
    const u32 lo = (u32)(((u64)cnt * (u64)blk) / NB_SEL);
    const u32 hi = (u32)(((u64)cnt * (u64)(blk + 1)) / NB_SEL);
    const u32* src = pkbase + pk_off(sidx) + (u32)(sb & 15) * cap;
    for (u32 i = lo + tid; i < hi; i += 256) {
      u32 key = src[i];
      if ((key >> hi_sh) == (pref >> hi_sh))
        atomicAdd(&hist_s[(key >> b_sh) & 255u], 1u);
    }
  }
  __syncthreads();
  if (hist_s[tid]) atomicAdd(&hist[sb * 256 + tid], hist_s[tid]);
  __syncthreads();                        // barrier drains all vmem (vmcnt(0))
  if (tid == 0) {
    __threadfence();
    u32 t = atomicAdd(&done[(level - 1) * 48 + sb], 1u);
    if (t == NB_SEL - 1) islast = 1;
  }
  __syncthreads();
  if (!islast) return;
  // ---- finisher (exactly one block per (scale,b))
  __threadfence();
  u32 hv = atomicAdd(&hist[sb * 256 + tid], 0u);    // atomic read
  cum[tid] = hv;
  hist[sb * 256 + tid] = 0;               // ready for next level
  __syncthreads();
  for (int off = 1; off < 256; off <<= 1) {
    u32 add = (tid + off < 256) ? cum[tid + off] : 0u;
    __syncthreads();
    cum[tid] += add;
    __syncthreads();
  }
  u32 r = act ? (u32)rank_s[sb] : 0u;
  u32 pref2 = act ? prefix_s[sb] : 0u;
  u32 cc = cum[tid];
  u32 cnext = (tid == 255) ? 0u : cum[tid + 1];
  __syncthreads();                        // snapshots before write
  if (act && r > 0 && cc >= r && cnext < r) {
    u32 np = pref2 | ((u32)tid << (24 - 8 * level));
    prefix_s[sb] = np;
    rank_s[sb] = (int)(r - cnext);
    if (level == 3) thresh[sb] = key2f(np);
  }
}

// ---------------------------------------------------------------------------
// K5a (merged): per-(scale,b,c) softmax stats. Grid: (8192, 3).
// ---------------------------------------------------------------------------
__global__ void k_softstats(const float* __restrict__ corrbase, const float* thresh,
                            float2* __restrict__ mZ) {
  __shared__ float row[1024];
  __shared__ float red_s[8];
  const int tid = threadIdx.x;
  const int bc = blockIdx.x;
  const int sidx = blockIdx.y;
  const int Ls = 1024 >> sidx;
  const float th = thresh[sidx * 16 + (bc >> 9)];
  const float* src = corrbase + co(sidx) + (size_t)bc * Ls;
  for (int t = tid; t < Ls; t += 256) row[t] = src[t];
  __syncthreads();
  float mx = 0.f;   // zeros always present in attn row -> true max >= 0
  for (int t = tid; t < Ls; t += 256) {
    float v = row[t];
    bool pk = (t >= 1) && (t <= Ls - 2) && (v > row[t - 1]) && (v > row[t + 1]) && (v >= th);
    if (pk) mx = fmaxf(mx, v);
  }
  for (int off = 32; off; off >>= 1) mx = fmaxf(mx, __shfl_down(mx, off, 64));
  if ((tid & 63) == 0) red_s[tid >> 6] = mx;
  __syncthreads();
  float m = fmaxf(fmaxf(red_s[0], red_s[1]), fmaxf(red_s[2], red_s[3]));
  float zs = 0.f;
  for (int t = tid; t < Ls; t += 256) {
    float v = row[t];
    bool pk = (t >= 1) && (t <= Ls - 2) && (v > row[t - 1]) && (v > row[t + 1]) && (v >= th);
    float a = pk ? v : 0.f;
    zs += __expf(a - m);
  }
  for (int off = 32; off; off >>= 1) zs += __shfl_down(zs, off, 64);
  if ((tid & 63) == 0) red_s[4 + (tid >> 6)] = zs;
  __syncthreads();
  if (tid == 0) {
    float Z = red_s[4] + red_s[5] + red_s[6] + red_s[7];
    mZ[sidx * 8192 + bc] = make_float2(m, 1.0f / Z);
  }
}

// ---------------------------------------------------------------------------
// K5b (s=2,4): o_s[b][tau][c] = softmax-weight * pooled v. 128-tau tiles.
// corr/mZ/thresh passed pre-offset for the scale.
// ---------------------------------------------------------------------------
__launch_bounds__(256, 4)
__global__ void k_apply(const float* __restrict__ corr, const float* __restrict__ V,
                        const float2* __restrict__ mZ, const float* thresh,
                        float* __restrict__ o, int Ls, int s) {
  __shared__ float ct[64][131];      // col j holds t = t0-1+j (clamped)
  __shared__ float m_s[64], rz_s[64];
  const int tid = threadIdx.x;
  const int b = blockIdx.z;
  const int c0 = blockIdx.y << 6;
  const int t0 = blockIdx.x << 7;
  {
    const int row0 = tid >> 7, jc = tid & 127;
    for (int rr = row0; rr < 64; rr += 2) {
      const float* src = corr + ((size_t)b * C_ + c0 + rr) * Ls;
      for (int j = jc; j < 130; j += 128) {
        int t = t0 - 1 + j;
        t = max(0, min(t, Ls - 1));
        ct[rr][j] = src[t];
      }
    }
  }
  if (tid < 64) {
    float2 v = mZ[b * C_ + c0 + tid];
    m_s[tid] = v.x; rz_s[tid] = v.y;
  }
  __syncthreads();
  const float th = thresh[b];
  const int cl = tid & 63, ts = tid >> 6;
  for (int ii = 0; ii < 32; ++ii) {
    int tl = ts + (ii << 2);
    int tg = t0 + tl;
    float vm = ct[cl][tl], vc = ct[cl][tl + 1], vp = ct[cl][tl + 2];
    bool pk = (tg >= 1) && (tg <= Ls - 2) && (vc > vm) && (vc > vp) && (vc >= th);
    float a = pk ? vc : 0.f;
    float w = __expf(a - m_s[cl]) * rz_s[cl];
    size_t vb = ((size_t)b * L_ + (size_t)tg * s) * C_ + c0 + cl;
    float vv;
    if (s == 2) vv = (V[vb] + V[vb + C_]) * 0.5f;
    else vv = ((V[vb] + V[vb + C_]) + (V[vb + 2 * C_] + V[vb + 3 * C_])) * 0.25f;
    o[((size_t)b * Ls + tg) * C_ + c0 + cl] = w * vv;
  }
}

// ---------------------------------------------------------------------------
// K5b-final (s=1): out = sw0*w*v + sw1*lerp(o2) + sw2*lerp(o4). 128-tau tiles.
// ---------------------------------------------------------------------------
__launch_bounds__(256, 4)
__global__ void k_apply_final(const float* __restrict__ corr, const float* __restrict__ V,
                              const float2* __restrict__ mZ, const float* thresh,
                              const float* __restrict__ o2, const float* __restrict__ o4,
                              const float* __restrict__ sw, float* __restrict__ out) {
  __shared__ float ct[64][131];
  __shared__ float m_s[64], rz_s[64];
  const int Ls = 1024;
  const int tid = threadIdx.x;
  const int b = blockIdx.z;
  const int c0 = blockIdx.y << 6;
  const int t0 = blockIdx.x << 7;
  {
    const int row0 = tid >> 7, jc = tid & 127;
    for (int rr = row0; rr < 64; rr += 2) {
      const float* src = corr + ((size_t)b * C_ + c0 + rr) * Ls;
      for (int j = jc; j < 130; j += 128) {
        int t = t0 - 1 + j;
        t = max(0, min(t, Ls - 1));
        ct[rr][j] = src[t];
      }
    }
  }
  if (tid < 64) {
    float2 v = mZ[b * C_ + c0 + tid];
    m_s[tid] = v.x; rz_s[tid] = v.y;
  }
  __syncthreads();
  const float th = thresh[b];
  const float sw0 = sw[0], sw1 = sw[1], sw2 = sw[2];
  const int cl = tid & 63, ts = tid >> 6;
  for (int ii = 0; ii < 32; ++ii) {
    int tl = ts + (ii << 2);
    int tg = t0 + tl;
    float vm = ct[cl][tl], vc = ct[cl][tl + 1], vp = ct[cl][tl + 2];
    bool pk = (tg >= 1) && (tg <= Ls - 2) && (vc > vm) && (vc > vp) && (vc >= th);
    float a = pk ? vc : 0.f;
    float w = __expf(a - m_s[cl]) * rz_s[cl];
    float v1 = V[((size_t)b * L_ + tg) * C_ + c0 + cl];
    float r = sw0 * w * v1;
    {
      float srcp = fmaxf((tg + 0.5f) * 0.5f - 0.5f, 0.f);
      int x0 = (int)srcp;
      float lam = srcp - (float)x0;
      int x1 = min(x0 + 1, 511);
      const float* p = o2 + (size_t)b * 512 * C_ + c0 + cl;
      r += sw1 * ((1.f - lam) * p[(size_t)x0 * C_] + lam * p[(size_t)x1 * C_]);
    }
    {
      float srcp = fmaxf((tg + 0.5f) * 0.25f - 0.5f, 0.f);
      int x0 = (int)srcp;
      float lam = srcp - (float)x0;
      int x1 = min(x0 + 1, 255);
      const float* p = o4 + (size_t)b * 256 * C_ + c0 + cl;
      r += sw2 * ((1.f - lam) * p[(size_t)x0 * C_] + lam * p[(size_t)x1 * C_]);
    }
    out[((size_t)b * L_ + tg) * C_ + c0 + cl] = r;
  }
}

// ---------------------------------------------------------------------------
extern "C" void kernel_launch(void* const* d_in, const int* in_sizes, int n_in,
                              void* d_out, int out_size, void* d_ws, size_t ws_size,
                              hipStream_t stream) {
  const float* Q  = (const float*)d_in[0];
  const float* Kk = (const float*)d_in[1];
  const float* V  = (const float*)d_in[2];
  const float* sw = (const float*)d_in[3];
  const float* w1 = (const float*)d_in[4];
  const float* b1 = (const float*)d_in[5];
  const float* w2 = (const float*)d_in[6];
  const float* b2 = (const float*)d_in[7];
  const float* w3 = (const float*)d_in[8];
  const float* b3 = (const float*)d_in[9];
  float* out = (float*)d_out;

  char* ws = (char*)d_ws;
  size_t p = 0;
  auto alloc = [&](size_t n) { char* r = ws + p; p = (p + n + 255) & ~(size_t)255; return r; };
  // corr for all 3 scales: [s1 | s2 | s4], elem offsets 0 / 8388608 / 12582912
  float*  corr = (float*)alloc((size_t)(8388608 + 4194304 + 2097152) * 4);  // 58.7 MB
  // o-region: o2 (16.8MB) + o4 (8.4MB); pk_buf (22.5MB) aliases it (pk dies
  // after k_sel level 3; o2/o4 born at k_apply, strictly later in-stream).
  char*   oreg = alloc((size_t)25165824);
  float*  o2   = (float*)oreg;
  float*  o4   = (float*)(oreg + 16777216);
  u32*    pk   = (u32*)oreg;
  float*  cm       = (float*)alloc(3 * 16 * 1024 * 4);
  float2* mZ       = (float2*)alloc(3 * 16 * 512 * 8);
  double* s1d      = (double*)alloc(48 * 8);
  double* s2d      = (double*)alloc(48 * 8);
  u32*    histA    = (u32*)alloc(3 * 16 * 256 * 4);
  u32*    histB    = (u32*)alloc(3 * 16 * 256 * 4);
  u32*    peak_cnt = (u32*)alloc(3 * 16 * 16 * 4);   // padded: 1 counter / 64B
  u32*    done     = (u32*)alloc(144 * 4);
  int*    rank_s   = (int*)alloc(48 * 4);
  u32*    prefix_s = (u32*)alloc(48 * 4);
  u32*    active   = (u32*)alloc(48 * 4);
  float*  thresh   = (float*)alloc(48 * 4);

  k_init<<<dim3(16), dim3(256), 0, stream>>>(histA, histB, peak_cnt, done,
                                             s1d, s2d, cm);
  k_corr<1><<<dim3(128, 8), dim3(256), 0, stream>>>(Q, Kk, corr);
  k_corr<2><<<dim3(128, 4), dim3(256), 0, stream>>>(Q, Kk, corr + 8388608);
  k_corr<4><<<dim3(128, 2), dim3(256), 0, stream>>>(Q, Kk, corr + 12582912);
  k_stats<<<dim3(C_ / GCH, B_, 3), dim3(256), 0, stream>>>(
      corr, cm, s1d, s2d, peak_cnt, histA, pk);
  k_mlp<<<dim3(48), dim3(256), 0, stream>>>(
      cm, s1d, s2d, peak_cnt, histA, rank_s, prefix_s, active, thresh,
      w1, b1, w2, b2, w3, b3);
  for (int level = 1; level <= 3; ++level)
    k_sel<<<dim3(48 * NB_SEL), dim3(256), 0, stream>>>(
        pk, peak_cnt, active, rank_s, prefix_s, histB, done, thresh, level);
  k_softstats<<<dim3(8192, 3), dim3(256), 0, stream>>>(corr, thresh, mZ);
  k_apply<<<dim3(2, 8, 16), dim3(256), 0, stream>>>(
      corr + 12582912, V, mZ + 2 * 8192, thresh + 32, o4, 256, 4);
  k_apply<<<dim3(4, 8, 16), dim3(256), 0, stream>>>(
      corr + 8388608, V, mZ + 1 * 8192, thresh + 16, o2, 512, 2);
  k_apply_final<<<dim3(8, 8, 16), dim3(256), 0, stream>>>(
      corr, V, mZ, thresh, o2, o4, sw, out);
}